// Round 1
// baseline (405.237 us; speedup 1.0000x reference)
//
#include <hip/hip_runtime.h>

#define IN_DIM 256
#define HID 32
#define HEADS 4
#define F1 128   // HEADS*HID

static __device__ __forceinline__ float leaky(float x){ return x > 0.f ? x : 0.2f*x; }

// ---------------- CSR build ----------------
__global__ void hist_kernel(const int* __restrict__ dsts, int* __restrict__ cnt, int E){
  int i = blockIdx.x*blockDim.x + threadIdx.x;
  if (i < E) atomicAdd(&cnt[dsts[i]], 1);
}

__device__ __forceinline__ int block_excl_scan(int v, int tid, int* total){
  __shared__ int ws[8];
  int lane = tid & 63, w = tid >> 6;
  int incl = v;
  #pragma unroll
  for (int d = 1; d < 64; d <<= 1){ int o = __shfl_up(incl, d); if (lane >= d) incl += o; }
  if (lane == 63) ws[w] = incl;
  __syncthreads();
  if (tid == 0){ int s = 0; for (int i = 0; i < 4; ++i){ int t = ws[i]; ws[i] = s; s += t; } ws[4] = s; }
  __syncthreads();
  *total = ws[4];
  return ws[w] + incl - v;   // exclusive
}

__global__ __launch_bounds__(256) void blocksum_kernel(const int* __restrict__ cnt, int* __restrict__ psum, int N){
  int i = blockIdx.x*256 + threadIdx.x;
  int v = (i < N) ? cnt[i] : 0;
  int tot; block_excl_scan(v, threadIdx.x, &tot);
  if (threadIdx.x == 0) psum[blockIdx.x] = tot;
}

__global__ __launch_bounds__(256) void scanpart_kernel(const int* __restrict__ psum, int* __restrict__ pexcl, int NB){
  int v = (threadIdx.x < NB) ? psum[threadIdx.x] : 0;
  int tot; int e = block_excl_scan(v, threadIdx.x, &tot);
  if (threadIdx.x < NB) pexcl[threadIdx.x] = e;
}

__global__ __launch_bounds__(256) void offsets_kernel(const int* __restrict__ cnt, const int* __restrict__ pexcl,
    int* __restrict__ offs, int* __restrict__ cursor, int N, int E){
  int i = blockIdx.x*256 + threadIdx.x;
  int v = (i < N) ? cnt[i] : 0;
  int tot; int e = block_excl_scan(v, threadIdx.x, &tot);
  int o = pexcl[blockIdx.x] + e;
  if (i < N){ offs[i] = o; cursor[i] = o; }
  if (blockIdx.x == 0 && threadIdx.x == 0) offs[N] = E;
}

__global__ void scatter_kernel(const int* __restrict__ srcs, const int* __restrict__ dsts,
    int* __restrict__ cursor, int* __restrict__ csr, int E){
  int i = blockIdx.x*blockDim.x + threadIdx.x;
  if (i < E){ int pos = atomicAdd(&cursor[dsts[i]], 1); csr[pos] = srcs[i]; }
}

// ---------------- GEMM1: h1 = x @ W1, fused att coefficients ----------------
// 64 rows x 128 cols per block, 256 threads, 8x4 per thread, K-chunk 16.
__global__ __launch_bounds__(256) void gemm1_kernel(const float* __restrict__ x, const float* __restrict__ W1,
    const float* __restrict__ att_src, const float* __restrict__ att_dst,
    float* __restrict__ h1, float* __restrict__ as1, float* __restrict__ ad1, int M){
  __shared__ float As[16][68];    // [k][row], pad 68 -> only free 2-way write conflicts
  __shared__ float Bs[16][128];   // [k][col]
  const int tid = threadIdx.x;
  const int cg = tid & 31;        // cols 4cg..4cg+3
  const int rg = tid >> 5;        // rows 8rg..8rg+7
  const int m0 = blockIdx.x * 64;
  float acc[8][4] = {};
  const int lr = tid >> 2;        // staging: row 0..63
  const int lq = tid & 3;         // staging: k-quad
  const int arow = m0 + lr;
  const bool aok = arow < M;
  const float* aptr = x + (size_t)arow * IN_DIM + 4*lq;

  for (int k0 = 0; k0 < IN_DIM; k0 += 16){
    float4 av = make_float4(0.f,0.f,0.f,0.f);
    if (aok) av = *(const float4*)(aptr + k0);
    float4 bv0 = *(const float4*)(W1 + (size_t)(k0 + (tid>>5))*F1 + 4*(tid&31));
    float4 bv1 = *(const float4*)(W1 + (size_t)(k0 + 8 + (tid>>5))*F1 + 4*(tid&31));
    As[4*lq+0][lr] = av.x; As[4*lq+1][lr] = av.y; As[4*lq+2][lr] = av.z; As[4*lq+3][lr] = av.w;
    *(float4*)&Bs[tid>>5][4*(tid&31)] = bv0;
    *(float4*)&Bs[(tid>>5)+8][4*(tid&31)] = bv1;
    __syncthreads();
    #pragma unroll
    for (int kk = 0; kk < 16; ++kk){
      float4 b  = *(const float4*)&Bs[kk][4*cg];
      float4 a0 = *(const float4*)&As[kk][8*rg];
      float4 a1 = *(const float4*)&As[kk][8*rg+4];
      float ar[8] = {a0.x,a0.y,a0.z,a0.w,a1.x,a1.y,a1.z,a1.w};
      #pragma unroll
      for (int i = 0; i < 8; ++i){
        acc[i][0] += ar[i]*b.x; acc[i][1] += ar[i]*b.y;
        acc[i][2] += ar[i]*b.z; acc[i][3] += ar[i]*b.w;
      }
    }
    __syncthreads();
  }

  const int head = cg >> 3;          // 4 cols all inside one head (32 cols/head)
  const int hc = (cg & 7) * 4;
  const float4 sv = *(const float4*)(att_src + head*HID + hc);
  const float4 dv = *(const float4*)(att_dst + head*HID + hc);
  #pragma unroll
  for (int i = 0; i < 8; ++i){
    int row = m0 + 8*rg + i;
    if (row < M){                      // uniform across the 8-lane shuffle group
      float4 o = make_float4(acc[i][0], acc[i][1], acc[i][2], acc[i][3]);
      *(float4*)(h1 + (size_t)row*F1 + 4*cg) = o;
      float ps = o.x*sv.x + o.y*sv.y + o.z*sv.z + o.w*sv.w;
      float pd = o.x*dv.x + o.y*dv.y + o.z*dv.z + o.w*dv.w;
      ps += __shfl_xor(ps,1); ps += __shfl_xor(ps,2); ps += __shfl_xor(ps,4);
      pd += __shfl_xor(pd,1); pd += __shfl_xor(pd,2); pd += __shfl_xor(pd,4);
      if ((cg & 7) == 0){ as1[row*4+head] = ps; ad1[row*4+head] = pd; }
    }
  }
}

// ---------------- Aggregation 1: softmax-weighted sum per dst node ----------------
// One wave per node; lane handles 2 channels (float2); denom kept in registers.
__global__ __launch_bounds__(256) void agg1_kernel(const float* __restrict__ h1,
    const float* __restrict__ a_s1, const float* __restrict__ a_d1,
    const int* __restrict__ offs, const int* __restrict__ csr,
    const float* __restrict__ b1, float* __restrict__ h1a, int N){
  int n = blockIdx.x*4 + (threadIdx.x >> 6);
  if (n >= N) return;
  int lane = threadIdx.x & 63;
  int ch = 2*lane, head = lane >> 4;
  float ad = a_d1[n*4+head];
  float2 acc = make_float2(0.f,0.f); float den = 0.f;
  { // self loop
    float p = __expf(leaky(a_s1[n*4+head] + ad));
    float2 hv = *(const float2*)(h1 + (size_t)n*F1 + ch);
    acc.x += p*hv.x; acc.y += p*hv.y; den += p;
  }
  int beg = offs[n], end = offs[n+1];
  for (int e = beg; e < end; ++e){
    int s = csr[e];
    float p = __expf(leaky(a_s1[s*4+head] + ad));
    float2 hv = *(const float2*)(h1 + (size_t)s*F1 + ch);
    acc.x += p*hv.x; acc.y += p*hv.y; den += p;
  }
  float inv = 1.f/den;
  float ox = acc.x*inv + b1[ch];
  float oy = acc.y*inv + b1[ch+1];
  ox = ox > 0.f ? ox : (__expf(ox) - 1.f);   // elu
  oy = oy > 0.f ? oy : (__expf(oy) - 1.f);
  *(float2*)(h1a + (size_t)n*F1 + ch) = make_float2(ox, oy);
}

// ---------------- GEMM2: h2 = h1a @ W2, fused att coefficients ----------------
// 64 rows x 32 cols per block, 256 threads, 4x2 per thread, full K=128 in LDS.
__global__ __launch_bounds__(256) void gemm2_kernel(const float* __restrict__ h1a, const float* __restrict__ W2,
    const float* __restrict__ att_src, const float* __restrict__ att_dst,
    float* __restrict__ h2, float* __restrict__ as2, float* __restrict__ ad2, int M){
  __shared__ float As[64*132];   // [row][k] pad 132
  __shared__ float Ws[128*32];   // [k][col]
  const int tid = threadIdx.x;
  const int cg = tid & 15;       // cols 2cg,2cg+1
  const int rg = tid >> 4;       // rows 4rg..4rg+3
  const int m0 = blockIdx.x*64;
  #pragma unroll
  for (int p = 0; p < 8; ++p){
    int i = tid + 256*p;
    int r = i >> 5, q = i & 31;
    int row = m0 + r;
    float4 v = make_float4(0.f,0.f,0.f,0.f);
    if (row < M) v = *(const float4*)(h1a + (size_t)row*F1 + 4*q);
    *(float4*)&As[r*132 + 4*q] = v;
  }
  #pragma unroll
  for (int p = 0; p < 4; ++p){
    int i = tid + 256*p;
    ((float4*)Ws)[i] = ((const float4*)W2)[i];
  }
  __syncthreads();
  float acc[4][2] = {};
  const float* a0p = &As[(4*rg+0)*132];
  const float* a1p = &As[(4*rg+1)*132];
  const float* a2p = &As[(4*rg+2)*132];
  const float* a3p = &As[(4*rg+3)*132];
  #pragma unroll 8
  for (int kk = 0; kk < 128; ++kk){
    float2 w = *(const float2*)&Ws[kk*32 + 2*cg];
    float a0 = a0p[kk], a1 = a1p[kk], a2 = a2p[kk], a3 = a3p[kk];
    acc[0][0]+=a0*w.x; acc[0][1]+=a0*w.y;
    acc[1][0]+=a1*w.x; acc[1][1]+=a1*w.y;
    acc[2][0]+=a2*w.x; acc[2][1]+=a2*w.y;
    acc[3][0]+=a3*w.x; acc[3][1]+=a3*w.y;
  }
  const float2 sv = *(const float2*)(att_src + 2*cg);
  const float2 dv = *(const float2*)(att_dst + 2*cg);
  #pragma unroll
  for (int i = 0; i < 4; ++i){
    int row = m0 + 4*rg + i;
    if (row < M){                     // uniform across the 16-lane shuffle group
      float2 o = make_float2(acc[i][0], acc[i][1]);
      *(float2*)(h2 + (size_t)row*HID + 2*cg) = o;
      float ps = o.x*sv.x + o.y*sv.y;
      float pd = o.x*dv.x + o.y*dv.y;
      ps += __shfl_xor(ps,1); ps += __shfl_xor(ps,2); ps += __shfl_xor(ps,4); ps += __shfl_xor(ps,8);
      pd += __shfl_xor(pd,1); pd += __shfl_xor(pd,2); pd += __shfl_xor(pd,4); pd += __shfl_xor(pd,8);
      if (cg == 0){ as2[row] = ps; ad2[row] = pd; }
    }
  }
}

// ---------------- Aggregation 2 + bias + elu + final linear ----------------
// Half-wave (32 lanes) per node; lane = channel; classifier via shuffle reduce.
__global__ __launch_bounds__(256) void agg2_kernel(const float* __restrict__ h2, const float* __restrict__ as2,
    const float* __restrict__ ad2, const int* __restrict__ offs, const int* __restrict__ csr,
    const float* __restrict__ b2, const float* __restrict__ linw, const float* __restrict__ linb,
    float* __restrict__ out, int N){
  int n = blockIdx.x*8 + (threadIdx.x >> 5);
  if (n >= N) return;
  int c = threadIdx.x & 31;
  float ad = ad2[n];
  float acc = 0.f, den = 0.f;
  { // self loop
    float p = __expf(leaky(as2[n] + ad));
    acc += p * h2[(size_t)n*HID + c]; den += p;
  }
  int beg = offs[n], end = offs[n+1];
  for (int e = beg; e < end; ++e){
    int s = csr[e];
    float p = __expf(leaky(as2[s] + ad));
    acc += p * h2[(size_t)s*HID + c]; den += p;
  }
  float o = acc/den + b2[c];
  o = o > 0.f ? o : (__expf(o) - 1.f);   // elu
  float r0 = o * linw[2*c+0];
  float r1 = o * linw[2*c+1];
  #pragma unroll
  for (int off = 1; off < 32; off <<= 1){
    r0 += __shfl_xor(r0, off, 32);
    r1 += __shfl_xor(r1, off, 32);
  }
  if (c == 0){
    out[(size_t)n*2+0] = r0 + linb[0];
    out[(size_t)n*2+1] = r1 + linb[1];
  }
}

// ---------------- launch ----------------
extern "C" void kernel_launch(void* const* d_in, const int* in_sizes, int n_in,
                              void* d_out, int out_size, void* d_ws, size_t ws_size,
                              hipStream_t stream) {
  const float* x    = (const float*)d_in[0];
  const int*   ei   = (const int*)  d_in[1];
  const float* W1   = (const float*)d_in[2];
  const float* as1w = (const float*)d_in[3];
  const float* ad1w = (const float*)d_in[4];
  const float* b1   = (const float*)d_in[5];
  const float* W2   = (const float*)d_in[6];
  const float* as2w = (const float*)d_in[7];
  const float* ad2w = (const float*)d_in[8];
  const float* b2   = (const float*)d_in[9];
  const float* linw = (const float*)d_in[10];
  const float* linb = (const float*)d_in[11];
  float* out = (float*)d_out;

  const int N = in_sizes[0] / IN_DIM;   // 50000
  const int E = in_sizes[1] / 2;        // 800000

  char* ws = (char*)d_ws;
  auto alloc = [&](size_t bytes) -> char* {
    char* p = ws; ws += (bytes + 255) & ~(size_t)255; return p;
  };
  float* h1   = (float*)alloc((size_t)N*F1*4);
  float* h1a  = (float*)alloc((size_t)N*F1*4);
  float* h2   = (float*)alloc((size_t)N*HID*4);
  float* a_s1 = (float*)alloc((size_t)N*4*4);
  float* a_d1 = (float*)alloc((size_t)N*4*4);
  float* a_s2 = (float*)alloc((size_t)N*4);
  float* a_d2 = (float*)alloc((size_t)N*4);
  int* cnt    = (int*)alloc((size_t)N*4);
  int* offs   = (int*)alloc((size_t)(N+1)*4);
  int* cursor = (int*)alloc((size_t)N*4);
  int* psum   = (int*)alloc(1024);
  int* pexcl  = (int*)alloc(1024);
  int* csr    = (int*)alloc((size_t)E*4);

  const int* srcs = ei;       // edge_index[0]
  const int* dsts = ei + E;   // edge_index[1]
  const int NB = (N + 255)/256;

  hipMemsetAsync(cnt, 0, (size_t)N*4, stream);
  hist_kernel<<<(E+255)/256, 256, 0, stream>>>(dsts, cnt, E);
  blocksum_kernel<<<NB, 256, 0, stream>>>(cnt, psum, N);
  scanpart_kernel<<<1, 256, 0, stream>>>(psum, pexcl, NB);
  offsets_kernel<<<NB, 256, 0, stream>>>(cnt, pexcl, offs, cursor, N, E);
  scatter_kernel<<<(E+255)/256, 256, 0, stream>>>(srcs, dsts, cursor, csr, E);
  gemm1_kernel<<<(N+63)/64, 256, 0, stream>>>(x, W1, as1w, ad1w, h1, a_s1, a_d1, N);
  agg1_kernel<<<(N+3)/4, 256, 0, stream>>>(h1, a_s1, a_d1, offs, csr, b1, h1a, N);
  gemm2_kernel<<<(N+63)/64, 256, 0, stream>>>(h1a, W2, as2w, ad2w, h2, a_s2, a_d2, N);
  agg2_kernel<<<(N+7)/8, 256, 0, stream>>>(h2, a_s2, a_d2, offs, csr, b2, linw, linb, out, N);
}

// Round 2
// 350.684 us; speedup vs baseline: 1.1556x; 1.1556x over previous
//
#include <hip/hip_runtime.h>

#define IN_DIM 256
#define HID 32
#define HEADS 4
#define F1 128   // HEADS*HID

static __device__ __forceinline__ float leaky(float x){ return x > 0.f ? x : 0.2f*x; }
static __device__ __forceinline__ float elu(float x){ return x > 0.f ? x : (__expf(x) - 1.f); }

// ---------------- CSR build ----------------
__global__ void hist_kernel(const int* __restrict__ dsts, int* __restrict__ cnt, int E){
  int i = blockIdx.x*blockDim.x + threadIdx.x;
  if (i < E) atomicAdd(&cnt[dsts[i]], 1);
}

__device__ __forceinline__ int block_excl_scan(int v, int tid, int* total){
  __shared__ int ws[8];
  int lane = tid & 63, w = tid >> 6;
  int incl = v;
  #pragma unroll
  for (int d = 1; d < 64; d <<= 1){ int o = __shfl_up(incl, d); if (lane >= d) incl += o; }
  if (lane == 63) ws[w] = incl;
  __syncthreads();
  if (tid == 0){ int s = 0; for (int i = 0; i < 4; ++i){ int t = ws[i]; ws[i] = s; s += t; } ws[4] = s; }
  __syncthreads();
  *total = ws[4];
  return ws[w] + incl - v;   // exclusive
}

__global__ __launch_bounds__(256) void blocksum_kernel(const int* __restrict__ cnt, int* __restrict__ psum, int N){
  int i = blockIdx.x*256 + threadIdx.x;
  int v = (i < N) ? cnt[i] : 0;
  int tot; block_excl_scan(v, threadIdx.x, &tot);
  if (threadIdx.x == 0) psum[blockIdx.x] = tot;
}

__global__ __launch_bounds__(256) void scanpart_kernel(const int* __restrict__ psum, int* __restrict__ pexcl, int NB){
  int v = (threadIdx.x < NB) ? psum[threadIdx.x] : 0;
  int tot; int e = block_excl_scan(v, threadIdx.x, &tot);
  if (threadIdx.x < NB) pexcl[threadIdx.x] = e;
}

__global__ __launch_bounds__(256) void offsets_kernel(const int* __restrict__ cnt, const int* __restrict__ pexcl,
    int* __restrict__ offs, int* __restrict__ cursor, int N, int E){
  int i = blockIdx.x*256 + threadIdx.x;
  int v = (i < N) ? cnt[i] : 0;
  int tot; int e = block_excl_scan(v, threadIdx.x, &tot);
  int o = pexcl[blockIdx.x] + e;
  if (i < N){ offs[i] = o; cursor[i] = o; }
  if (blockIdx.x == 0 && threadIdx.x == 0) offs[N] = E;
}

__global__ void scatter_kernel(const int* __restrict__ srcs, const int* __restrict__ dsts,
    int* __restrict__ cursor, int* __restrict__ csr, int E){
  int i = blockIdx.x*blockDim.x + threadIdx.x;
  if (i < E){ int pos = atomicAdd(&cursor[dsts[i]], 1); csr[pos] = srcs[i]; }
}

// ---------------- GEMM1: h1 = x @ W1, fused att coefficients ----------------
__global__ __launch_bounds__(256) void gemm1_kernel(const float* __restrict__ x, const float* __restrict__ W1,
    const float* __restrict__ att_src, const float* __restrict__ att_dst,
    float* __restrict__ h1, float* __restrict__ as1, float* __restrict__ ad1, int M){
  __shared__ float As[16][68];    // [k][row]
  __shared__ float Bs[16][128];   // [k][col]
  const int tid = threadIdx.x;
  const int cg = tid & 31;        // cols 4cg..4cg+3
  const int rg = tid >> 5;        // rows 8rg..8rg+7
  const int m0 = blockIdx.x * 64;
  float acc[8][4] = {};
  const int lr = tid >> 2;        // staging: row 0..63
  const int lq = tid & 3;         // staging: k-quad
  const int arow = m0 + lr;
  const bool aok = arow < M;
  const float* aptr = x + (size_t)arow * IN_DIM + 4*lq;

  for (int k0 = 0; k0 < IN_DIM; k0 += 16){
    float4 av = make_float4(0.f,0.f,0.f,0.f);
    if (aok) av = *(const float4*)(aptr + k0);
    float4 bv0 = *(const float4*)(W1 + (size_t)(k0 + (tid>>5))*F1 + 4*(tid&31));
    float4 bv1 = *(const float4*)(W1 + (size_t)(k0 + 8 + (tid>>5))*F1 + 4*(tid&31));
    As[4*lq+0][lr] = av.x; As[4*lq+1][lr] = av.y; As[4*lq+2][lr] = av.z; As[4*lq+3][lr] = av.w;
    *(float4*)&Bs[tid>>5][4*(tid&31)] = bv0;
    *(float4*)&Bs[(tid>>5)+8][4*(tid&31)] = bv1;
    __syncthreads();
    #pragma unroll
    for (int kk = 0; kk < 16; ++kk){
      float4 b  = *(const float4*)&Bs[kk][4*cg];
      float4 a0 = *(const float4*)&As[kk][8*rg];
      float4 a1 = *(const float4*)&As[kk][8*rg+4];
      float ar[8] = {a0.x,a0.y,a0.z,a0.w,a1.x,a1.y,a1.z,a1.w};
      #pragma unroll
      for (int i = 0; i < 8; ++i){
        acc[i][0] += ar[i]*b.x; acc[i][1] += ar[i]*b.y;
        acc[i][2] += ar[i]*b.z; acc[i][3] += ar[i]*b.w;
      }
    }
    __syncthreads();
  }

  const int head = cg >> 3;
  const int hc = (cg & 7) * 4;
  const float4 sv = *(const float4*)(att_src + head*HID + hc);
  const float4 dv = *(const float4*)(att_dst + head*HID + hc);
  #pragma unroll
  for (int i = 0; i < 8; ++i){
    int row = m0 + 8*rg + i;
    if (row < M){
      float4 o = make_float4(acc[i][0], acc[i][1], acc[i][2], acc[i][3]);
      *(float4*)(h1 + (size_t)row*F1 + 4*cg) = o;
      float ps = o.x*sv.x + o.y*sv.y + o.z*sv.z + o.w*sv.w;
      float pd = o.x*dv.x + o.y*dv.y + o.z*dv.z + o.w*dv.w;
      ps += __shfl_xor(ps,1); ps += __shfl_xor(ps,2); ps += __shfl_xor(ps,4);
      pd += __shfl_xor(pd,1); pd += __shfl_xor(pd,2); pd += __shfl_xor(pd,4);
      if ((cg & 7) == 0){ as1[row*4+head] = ps; ad1[row*4+head] = pd; }
    }
  }
}

// ---------------- Aggregation 1 ----------------
// One wave per node; 2 edge-subgroups x 32 lanes; lane holds float4 (4 channels).
// 4-edge unroll per subgroup -> up to 8 gather rows in flight per wave.
__global__ __launch_bounds__(256) void agg1_kernel(const float* __restrict__ h1,
    const float* __restrict__ a_s1, const float* __restrict__ a_d1,
    const int* __restrict__ offs, const int* __restrict__ csr,
    const float* __restrict__ b1, float* __restrict__ h1a, int N){
  int n = blockIdx.x*4 + (threadIdx.x >> 6);
  if (n >= N) return;
  const int lane = threadIdx.x & 63;
  const int sub  = lane >> 5;       // edge subgroup 0/1
  const int cl   = lane & 31;       // channel-lane
  const int ch   = 4*cl;
  const int head = cl >> 3;         // 32 channels per head, 4 per lane
  const float ad = a_d1[n*4+head];
  float ax=0.f, ay=0.f, az=0.f, aw=0.f, den=0.f;
  if (sub == 0){ // self loop
    float p = __expf(leaky(a_s1[n*4+head] + ad));
    float4 hv = *(const float4*)(h1 + (size_t)n*F1 + ch);
    ax = p*hv.x; ay = p*hv.y; az = p*hv.z; aw = p*hv.w; den = p;
  }
  const int beg = offs[n], end = offs[n+1];
  int e = beg + sub;
  for (; e + 6 < end; e += 8){
    int s0 = csr[e], s1 = csr[e+2], s2 = csr[e+4], s3 = csr[e+6];
    float p0 = __expf(leaky(a_s1[s0*4+head] + ad));
    float p1 = __expf(leaky(a_s1[s1*4+head] + ad));
    float p2 = __expf(leaky(a_s1[s2*4+head] + ad));
    float p3 = __expf(leaky(a_s1[s3*4+head] + ad));
    float4 v0 = *(const float4*)(h1 + (size_t)s0*F1 + ch);
    float4 v1 = *(const float4*)(h1 + (size_t)s1*F1 + ch);
    float4 v2 = *(const float4*)(h1 + (size_t)s2*F1 + ch);
    float4 v3 = *(const float4*)(h1 + (size_t)s3*F1 + ch);
    ax += p0*v0.x + p1*v1.x + p2*v2.x + p3*v3.x;
    ay += p0*v0.y + p1*v1.y + p2*v2.y + p3*v3.y;
    az += p0*v0.z + p1*v1.z + p2*v2.z + p3*v3.z;
    aw += p0*v0.w + p1*v1.w + p2*v2.w + p3*v3.w;
    den += p0 + p1 + p2 + p3;
  }
  for (; e < end; e += 2){
    int s = csr[e];
    float p = __expf(leaky(a_s1[s*4+head] + ad));
    float4 v = *(const float4*)(h1 + (size_t)s*F1 + ch);
    ax += p*v.x; ay += p*v.y; az += p*v.z; aw += p*v.w; den += p;
  }
  // combine the two subgroups
  ax += __shfl_xor(ax,32); ay += __shfl_xor(ay,32);
  az += __shfl_xor(az,32); aw += __shfl_xor(aw,32);
  den += __shfl_xor(den,32);
  if (sub == 0){
    float inv = 1.f/den;
    float4 bv = *(const float4*)(b1 + ch);
    float o0 = elu(ax*inv + bv.x);
    float o1 = elu(ay*inv + bv.y);
    float o2 = elu(az*inv + bv.z);
    float o3 = elu(aw*inv + bv.w);
    *(float4*)(h1a + (size_t)n*F1 + ch) = make_float4(o0,o1,o2,o3);
  }
}

// ---------------- GEMM2: h2 = h1a @ W2, fused att coefficients ----------------
__global__ __launch_bounds__(256) void gemm2_kernel(const float* __restrict__ h1a, const float* __restrict__ W2,
    const float* __restrict__ att_src, const float* __restrict__ att_dst,
    float* __restrict__ h2, float* __restrict__ as2, float* __restrict__ ad2, int M){
  __shared__ float As[64*132];   // [row][k] pad 132
  __shared__ float Ws[128*32];   // [k][col]
  const int tid = threadIdx.x;
  const int cg = tid & 15;       // cols 2cg,2cg+1
  const int rg = tid >> 4;       // rows 4rg..4rg+3
  const int m0 = blockIdx.x*64;
  #pragma unroll
  for (int p = 0; p < 8; ++p){
    int i = tid + 256*p;
    int r = i >> 5, q = i & 31;
    int row = m0 + r;
    float4 v = make_float4(0.f,0.f,0.f,0.f);
    if (row < M) v = *(const float4*)(h1a + (size_t)row*F1 + 4*q);
    *(float4*)&As[r*132 + 4*q] = v;
  }
  #pragma unroll
  for (int p = 0; p < 4; ++p){
    int i = tid + 256*p;
    ((float4*)Ws)[i] = ((const float4*)W2)[i];
  }
  __syncthreads();
  float acc[4][2] = {};
  const float* a0p = &As[(4*rg+0)*132];
  const float* a1p = &As[(4*rg+1)*132];
  const float* a2p = &As[(4*rg+2)*132];
  const float* a3p = &As[(4*rg+3)*132];
  #pragma unroll 8
  for (int kk = 0; kk < 128; ++kk){
    float2 w = *(const float2*)&Ws[kk*32 + 2*cg];
    float a0 = a0p[kk], a1 = a1p[kk], a2 = a2p[kk], a3 = a3p[kk];
    acc[0][0]+=a0*w.x; acc[0][1]+=a0*w.y;
    acc[1][0]+=a1*w.x; acc[1][1]+=a1*w.y;
    acc[2][0]+=a2*w.x; acc[2][1]+=a2*w.y;
    acc[3][0]+=a3*w.x; acc[3][1]+=a3*w.y;
  }
  const float2 sv = *(const float2*)(att_src + 2*cg);
  const float2 dv = *(const float2*)(att_dst + 2*cg);
  #pragma unroll
  for (int i = 0; i < 4; ++i){
    int row = m0 + 4*rg + i;
    if (row < M){
      float2 o = make_float2(acc[i][0], acc[i][1]);
      *(float2*)(h2 + (size_t)row*HID + 2*cg) = o;
      float ps = o.x*sv.x + o.y*sv.y;
      float pd = o.x*dv.x + o.y*dv.y;
      ps += __shfl_xor(ps,1); ps += __shfl_xor(ps,2); ps += __shfl_xor(ps,4); ps += __shfl_xor(ps,8);
      pd += __shfl_xor(pd,1); pd += __shfl_xor(pd,2); pd += __shfl_xor(pd,4); pd += __shfl_xor(pd,8);
      if (cg == 0){ as2[row] = ps; ad2[row] = pd; }
    }
  }
}

// ---------------- Aggregation 2 + bias + elu + final linear ----------------
// One wave per node; 8 edge-subgroups x 8 lanes; lane holds float4 (4 channels).
// 2-edge unroll per subgroup -> up to 16 gather rows in flight per wave.
__global__ __launch_bounds__(256) void agg2_kernel(const float* __restrict__ h2, const float* __restrict__ as2,
    const float* __restrict__ ad2, const int* __restrict__ offs, const int* __restrict__ csr,
    const float* __restrict__ b2, const float* __restrict__ linw, const float* __restrict__ linb,
    float* __restrict__ out, int N){
  int n = blockIdx.x*4 + (threadIdx.x >> 6);
  if (n >= N) return;
  const int lane = threadIdx.x & 63;
  const int sub  = lane >> 3;       // edge subgroup 0..7
  const int cl   = lane & 7;        // channel-lane
  const int ch   = 4*cl;
  const float ad = ad2[n];
  float ax=0.f, ay=0.f, az=0.f, aw=0.f, den=0.f;
  if (sub == 0){ // self loop
    float p = __expf(leaky(as2[n] + ad));
    float4 hv = *(const float4*)(h2 + (size_t)n*HID + ch);
    ax = p*hv.x; ay = p*hv.y; az = p*hv.z; aw = p*hv.w; den = p;
  }
  const int beg = offs[n], end = offs[n+1];
  int e = beg + sub;
  for (; e + 8 < end; e += 16){
    int s0 = csr[e], s1 = csr[e+8];
    float p0 = __expf(leaky(as2[s0] + ad));
    float p1 = __expf(leaky(as2[s1] + ad));
    float4 v0 = *(const float4*)(h2 + (size_t)s0*HID + ch);
    float4 v1 = *(const float4*)(h2 + (size_t)s1*HID + ch);
    ax += p0*v0.x + p1*v1.x;
    ay += p0*v0.y + p1*v1.y;
    az += p0*v0.z + p1*v1.z;
    aw += p0*v0.w + p1*v1.w;
    den += p0 + p1;
  }
  for (; e < end; e += 8){
    int s = csr[e];
    float p = __expf(leaky(as2[s] + ad));
    float4 v = *(const float4*)(h2 + (size_t)s*HID + ch);
    ax += p*v.x; ay += p*v.y; az += p*v.z; aw += p*v.w; den += p;
  }
  // reduce across the 8 subgroups
  #pragma unroll
  for (int off = 8; off < 64; off <<= 1){
    ax += __shfl_xor(ax,off); ay += __shfl_xor(ay,off);
    az += __shfl_xor(az,off); aw += __shfl_xor(aw,off);
    den += __shfl_xor(den,off);
  }
  float inv = 1.f/den;
  float o0 = elu(ax*inv + b2[ch+0]);
  float o1 = elu(ay*inv + b2[ch+1]);
  float o2 = elu(az*inv + b2[ch+2]);
  float o3 = elu(aw*inv + b2[ch+3]);
  float r0 = o0*linw[2*(ch+0)]   + o1*linw[2*(ch+1)]   + o2*linw[2*(ch+2)]   + o3*linw[2*(ch+3)];
  float r1 = o0*linw[2*(ch+0)+1] + o1*linw[2*(ch+1)+1] + o2*linw[2*(ch+2)+1] + o3*linw[2*(ch+3)+1];
  r0 += __shfl_xor(r0,1); r0 += __shfl_xor(r0,2); r0 += __shfl_xor(r0,4);
  r1 += __shfl_xor(r1,1); r1 += __shfl_xor(r1,2); r1 += __shfl_xor(r1,4);
  if (lane == 0){
    out[(size_t)n*2+0] = r0 + linb[0];
    out[(size_t)n*2+1] = r1 + linb[1];
  }
}

// ---------------- launch ----------------
extern "C" void kernel_launch(void* const* d_in, const int* in_sizes, int n_in,
                              void* d_out, int out_size, void* d_ws, size_t ws_size,
                              hipStream_t stream) {
  const float* x    = (const float*)d_in[0];
  const int*   ei   = (const int*)  d_in[1];
  const float* W1   = (const float*)d_in[2];
  const float* as1w = (const float*)d_in[3];
  const float* ad1w = (const float*)d_in[4];
  const float* b1   = (const float*)d_in[5];
  const float* W2   = (const float*)d_in[6];
  const float* as2w = (const float*)d_in[7];
  const float* ad2w = (const float*)d_in[8];
  const float* b2   = (const float*)d_in[9];
  const float* linw = (const float*)d_in[10];
  const float* linb = (const float*)d_in[11];
  float* out = (float*)d_out;

  const int N = in_sizes[0] / IN_DIM;   // 50000
  const int E = in_sizes[1] / 2;        // 800000

  char* ws = (char*)d_ws;
  auto alloc = [&](size_t bytes) -> char* {
    char* p = ws; ws += (bytes + 255) & ~(size_t)255; return p;
  };
  float* h1   = (float*)alloc((size_t)N*F1*4);
  float* h1a  = (float*)alloc((size_t)N*F1*4);
  float* h2   = (float*)alloc((size_t)N*HID*4);
  float* a_s1 = (float*)alloc((size_t)N*4*4);
  float* a_d1 = (float*)alloc((size_t)N*4*4);
  float* a_s2 = (float*)alloc((size_t)N*4);
  float* a_d2 = (float*)alloc((size_t)N*4);
  int* cnt    = (int*)alloc((size_t)N*4);
  int* offs   = (int*)alloc((size_t)(N+1)*4);
  int* cursor = (int*)alloc((size_t)N*4);
  int* psum   = (int*)alloc(1024);
  int* pexcl  = (int*)alloc(1024);
  int* csr    = (int*)alloc((size_t)E*4);

  const int* srcs = ei;       // edge_index[0]
  const int* dsts = ei + E;   // edge_index[1]
  const int NB = (N + 255)/256;

  hipMemsetAsync(cnt, 0, (size_t)N*4, stream);
  hist_kernel<<<(E+255)/256, 256, 0, stream>>>(dsts, cnt, E);
  blocksum_kernel<<<NB, 256, 0, stream>>>(cnt, psum, N);
  scanpart_kernel<<<1, 256, 0, stream>>>(psum, pexcl, NB);
  offsets_kernel<<<NB, 256, 0, stream>>>(cnt, pexcl, offs, cursor, N, E);
  scatter_kernel<<<(E+255)/256, 256, 0, stream>>>(srcs, dsts, cursor, csr, E);
  gemm1_kernel<<<(N+63)/64, 256, 0, stream>>>(x, W1, as1w, ad1w, h1, a_s1, a_d1, N);
  agg1_kernel<<<(N+3)/4, 256, 0, stream>>>(h1, a_s1, a_d1, offs, csr, b1, h1a, N);
  gemm2_kernel<<<(N+63)/64, 256, 0, stream>>>(h1a, W2, as2w, ad2w, h2, a_s2, a_d2, N);
  agg2_kernel<<<(N+3)/4, 256, 0, stream>>>(h2, a_s2, a_d2, offs, csr, b2, linw, linb, out, N);
}

// Round 4
// 321.646 us; speedup vs baseline: 1.2599x; 1.0903x over previous
//
#include <hip/hip_runtime.h>

#define IN_DIM 256
#define HID 32
#define HEADS 4
#define F1 128   // HEADS*HID

static __device__ __forceinline__ float leaky(float x){ return x > 0.f ? x : 0.2f*x; }
static __device__ __forceinline__ float elu(float x){ return x > 0.f ? x : (__expf(x) - 1.f); }

// bf16 helpers (round-to-nearest-even)
static __device__ __forceinline__ unsigned short f2bf(float f){
  unsigned int u = __float_as_uint(f);
  u += 0x7FFFu + ((u >> 16) & 1u);
  return (unsigned short)(u >> 16);
}
static __device__ __forceinline__ float bf2f(unsigned short h){
  return __uint_as_float(((unsigned int)h) << 16);
}
static __device__ __forceinline__ unsigned int pack2(unsigned short a, unsigned short b){
  return (unsigned int)a | ((unsigned int)b << 16);
}

// ---------------- CSR build ----------------
__global__ void hist_kernel(const int* __restrict__ dsts, int* __restrict__ cnt, int E){
  int i = blockIdx.x*blockDim.x + threadIdx.x;
  if (i < E) atomicAdd(&cnt[dsts[i]], 1);
}

__device__ __forceinline__ int block_excl_scan(int v, int tid, int* total){
  __shared__ int ws[8];
  int lane = tid & 63, w = tid >> 6;
  int incl = v;
  #pragma unroll
  for (int d = 1; d < 64; d <<= 1){ int o = __shfl_up(incl, d); if (lane >= d) incl += o; }
  if (lane == 63) ws[w] = incl;
  __syncthreads();
  if (tid == 0){ int s = 0; for (int i = 0; i < 4; ++i){ int t = ws[i]; ws[i] = s; s += t; } ws[4] = s; }
  __syncthreads();
  *total = ws[4];
  return ws[w] + incl - v;   // exclusive
}

__global__ __launch_bounds__(256) void blocksum_kernel(const int* __restrict__ cnt, int* __restrict__ psum, int N){
  int i = blockIdx.x*256 + threadIdx.x;
  int v = (i < N) ? cnt[i] : 0;
  int tot; block_excl_scan(v, threadIdx.x, &tot);
  if (threadIdx.x == 0) psum[blockIdx.x] = tot;
}

__global__ __launch_bounds__(256) void scanpart_kernel(const int* __restrict__ psum, int* __restrict__ pexcl, int NB){
  int v = (threadIdx.x < NB) ? psum[threadIdx.x] : 0;
  int tot; int e = block_excl_scan(v, threadIdx.x, &tot);
  if (threadIdx.x < NB) pexcl[threadIdx.x] = e;
}

__global__ __launch_bounds__(256) void offsets_kernel(const int* __restrict__ cnt, const int* __restrict__ pexcl,
    int* __restrict__ offs, int* __restrict__ cursor, int N, int E){
  int i = blockIdx.x*256 + threadIdx.x;
  int v = (i < N) ? cnt[i] : 0;
  int tot; int e = block_excl_scan(v, threadIdx.x, &tot);
  int o = pexcl[blockIdx.x] + e;
  if (i < N){ offs[i] = o; cursor[i] = o; }
  if (blockIdx.x == 0 && threadIdx.x == 0) offs[N] = E;
}

__global__ void scatter_kernel(const int* __restrict__ srcs, const int* __restrict__ dsts,
    int* __restrict__ cursor, int* __restrict__ csr, int E){
  int i = blockIdx.x*blockDim.x + threadIdx.x;
  if (i < E){ int pos = atomicAdd(&cursor[dsts[i]], 1); csr[pos] = srcs[i]; }
}

// ---------------- W1 convert: f32 [k][n] -> bf16 hi/lo transposed [n][k] ----------------
// NOTE: Wh/Wl live in the (dead-after-offsets_kernel) cnt region of d_ws.
__global__ __launch_bounds__(256) void convw_kernel(const float* __restrict__ W1,
    unsigned short* __restrict__ Wh, unsigned short* __restrict__ Wl){
  int i = blockIdx.x*256 + threadIdx.x;      // 0..32767
  int n = i >> 8, k = i & 255;
  float w = W1[(size_t)k*F1 + n];
  unsigned short h = f2bf(w);
  Wh[i] = h;
  Wl[i] = f2bf(w - bf2f(h));
}

// ---------------- GEMM1 (MFMA bf16 split): h1 = x @ W1, fused att coefficients ----------------
// Block: 64 rows x 128 cols. 4 waves, each 32x64 = 2x4 tiles of 16x16x32. 3 MFMA per tile per K-iter.
typedef __attribute__((ext_vector_type(8))) short bf8_t;
typedef __attribute__((ext_vector_type(4))) float f4_t;

__global__ __launch_bounds__(256) void gemm1_kernel(const float* __restrict__ x,
    const unsigned short* __restrict__ Wh, const unsigned short* __restrict__ Wl,
    const float* __restrict__ att_src, const float* __restrict__ att_dst,
    float* __restrict__ h1, float* __restrict__ as1, float* __restrict__ ad1, int M){
  // LDS as uint4 rows: 5 x 16B = 80B per row = 40 ushorts (32 data + 8 pad; 2-way conflicts only = free).
  __shared__ uint4 AhV[64][5], AlV[64][5];    // [row][k-chunk]
  __shared__ uint4 BhV[128][5], BlV[128][5];  // [n][k-chunk]
  const int tid = threadIdx.x;
  const int m0 = blockIdx.x*64;
  const int wave = tid >> 6, lane = tid & 63;
  const int quad = lane >> 4, l16 = lane & 15;
  const int wr = (wave & 1)*32;    // wave row base
  const int wc = (wave >> 1)*64;   // wave col base
  f4_t acc[2][4];
  #pragma unroll
  for (int r = 0; r < 2; ++r)
    #pragma unroll
    for (int c = 0; c < 4; ++c)
      #pragma unroll
      for (int i = 0; i < 4; ++i) acc[r][c][i] = 0.f;

  // staging assignments
  const int ar = tid >> 2, akc = tid & 3;        // A: row, k-chunk (8 floats each)
  const bool aok = (m0 + ar) < M;
  const float* ap = x + (size_t)(m0 + ar)*IN_DIM + 8*akc;
  const int bn = tid >> 1, bkc = (tid & 1)*2;    // B: col n, k-chunks bkc, bkc+1
  const unsigned short* bph = Wh + (size_t)bn*256 + 16*(tid & 1);
  const unsigned short* bpl = Wl + (size_t)bn*256 + 16*(tid & 1);

  for (int k0 = 0; k0 < IN_DIM; k0 += 32){
    float4 a0 = make_float4(0.f,0.f,0.f,0.f), a1 = a0;
    if (aok){ a0 = *(const float4*)(ap + k0); a1 = *(const float4*)(ap + k0 + 4); }
    float v[8] = {a0.x,a0.y,a0.z,a0.w,a1.x,a1.y,a1.z,a1.w};
    unsigned short hh[8], ll[8];
    #pragma unroll
    for (int j = 0; j < 8; ++j){
      unsigned short h = f2bf(v[j]); hh[j] = h; ll[j] = f2bf(v[j] - bf2f(h));
    }
    uint4 hv; hv.x = pack2(hh[0],hh[1]); hv.y = pack2(hh[2],hh[3]); hv.z = pack2(hh[4],hh[5]); hv.w = pack2(hh[6],hh[7]);
    uint4 lv; lv.x = pack2(ll[0],ll[1]); lv.y = pack2(ll[2],ll[3]); lv.z = pack2(ll[4],ll[5]); lv.w = pack2(ll[6],ll[7]);
    AhV[ar][akc] = hv;
    AlV[ar][akc] = lv;
    BhV[bn][bkc+0] = *(const uint4*)(bph + k0);
    BhV[bn][bkc+1] = *(const uint4*)(bph + k0 + 8);
    BlV[bn][bkc+0] = *(const uint4*)(bpl + k0);
    BlV[bn][bkc+1] = *(const uint4*)(bpl + k0 + 8);
    __syncthreads();

    bf8_t arh[2], arl[2], brh[4], brl[4];
    #pragma unroll
    for (int r = 0; r < 2; ++r){
      arh[r] = *(const bf8_t*)&AhV[wr + r*16 + l16][quad];
      arl[r] = *(const bf8_t*)&AlV[wr + r*16 + l16][quad];
    }
    #pragma unroll
    for (int c = 0; c < 4; ++c){
      brh[c] = *(const bf8_t*)&BhV[wc + c*16 + l16][quad];
      brl[c] = *(const bf8_t*)&BlV[wc + c*16 + l16][quad];
    }
    #pragma unroll
    for (int r = 0; r < 2; ++r)
      #pragma unroll
      for (int c = 0; c < 4; ++c){
        acc[r][c] = __builtin_amdgcn_mfma_f32_16x16x32_bf16(arh[r], brh[c], acc[r][c], 0, 0, 0);
        acc[r][c] = __builtin_amdgcn_mfma_f32_16x16x32_bf16(arh[r], brl[c], acc[r][c], 0, 0, 0);
        acc[r][c] = __builtin_amdgcn_mfma_f32_16x16x32_bf16(arl[r], brh[c], acc[r][c], 0, 0, 0);
      }
    __syncthreads();
  }

  // epilogue: C/D layout col = l16, row = quad*4 + i (within each 16x16 tile)
  const int head0 = wc >> 5;   // wave covers heads head0, head0+1
  float sv[4], dv[4];
  #pragma unroll
  for (int c = 0; c < 4; ++c){
    int col_in_head = (c & 1)*16 + l16;
    sv[c] = att_src[(head0 + (c >> 1))*HID + col_in_head];
    dv[c] = att_dst[(head0 + (c >> 1))*HID + col_in_head];
  }
  #pragma unroll
  for (int r = 0; r < 2; ++r){
    #pragma unroll
    for (int i = 0; i < 4; ++i){
      int row = m0 + wr + r*16 + quad*4 + i;
      bool ok = row < M;
      float hv0 = acc[r][0][i], hv1 = acc[r][1][i], hv2 = acc[r][2][i], hv3 = acc[r][3][i];
      if (ok){
        float* hp = h1 + (size_t)row*F1 + wc + l16;
        hp[0]  = hv0; hp[16] = hv1; hp[32] = hv2; hp[48] = hv3;
      }
      float p0 = hv0*sv[0] + hv1*sv[1];
      float p1 = hv2*sv[2] + hv3*sv[3];
      float q0 = hv0*dv[0] + hv1*dv[1];
      float q1 = hv2*dv[2] + hv3*dv[3];
      p0 += __shfl_xor(p0,1); p0 += __shfl_xor(p0,2); p0 += __shfl_xor(p0,4); p0 += __shfl_xor(p0,8);
      p1 += __shfl_xor(p1,1); p1 += __shfl_xor(p1,2); p1 += __shfl_xor(p1,4); p1 += __shfl_xor(p1,8);
      q0 += __shfl_xor(q0,1); q0 += __shfl_xor(q0,2); q0 += __shfl_xor(q0,4); q0 += __shfl_xor(q0,8);
      q1 += __shfl_xor(q1,1); q1 += __shfl_xor(q1,2); q1 += __shfl_xor(q1,4); q1 += __shfl_xor(q1,8);
      if (ok && l16 == 0){
        as1[row*4 + head0]     = p0;
        as1[row*4 + head0 + 1] = p1;
        ad1[row*4 + head0]     = q0;
        ad1[row*4 + head0 + 1] = q1;
      }
    }
  }
}

// ---------------- Aggregation 1 ----------------
__global__ __launch_bounds__(256) void agg1_kernel(const float* __restrict__ h1,
    const float* __restrict__ a_s1, const float* __restrict__ a_d1,
    const int* __restrict__ offs, const int* __restrict__ csr,
    const float* __restrict__ b1, float* __restrict__ h1a, int N){
  int n = blockIdx.x*4 + (threadIdx.x >> 6);
  if (n >= N) return;
  const int lane = threadIdx.x & 63;
  const int sub  = lane >> 5;       // edge subgroup 0/1
  const int cl   = lane & 31;       // channel-lane
  const int ch   = 4*cl;
  const int head = cl >> 3;
  const float ad = a_d1[n*4+head];
  float ax=0.f, ay=0.f, az=0.f, aw=0.f, den=0.f;
  if (sub == 0){ // self loop
    float p = __expf(leaky(a_s1[n*4+head] + ad));
    float4 hv = *(const float4*)(h1 + (size_t)n*F1 + ch);
    ax = p*hv.x; ay = p*hv.y; az = p*hv.z; aw = p*hv.w; den = p;
  }
  const int beg = offs[n], end = offs[n+1];
  int e = beg + sub;
  for (; e + 6 < end; e += 8){
    int s0 = csr[e], s1 = csr[e+2], s2 = csr[e+4], s3 = csr[e+6];
    float p0 = __expf(leaky(a_s1[s0*4+head] + ad));
    float p1 = __expf(leaky(a_s1[s1*4+head] + ad));
    float p2 = __expf(leaky(a_s1[s2*4+head] + ad));
    float p3 = __expf(leaky(a_s1[s3*4+head] + ad));
    float4 v0 = *(const float4*)(h1 + (size_t)s0*F1 + ch);
    float4 v1 = *(const float4*)(h1 + (size_t)s1*F1 + ch);
    float4 v2 = *(const float4*)(h1 + (size_t)s2*F1 + ch);
    float4 v3 = *(const float4*)(h1 + (size_t)s3*F1 + ch);
    ax += p0*v0.x + p1*v1.x + p2*v2.x + p3*v3.x;
    ay += p0*v0.y + p1*v1.y + p2*v2.y + p3*v3.y;
    az += p0*v0.z + p1*v1.z + p2*v2.z + p3*v3.z;
    aw += p0*v0.w + p1*v1.w + p2*v2.w + p3*v3.w;
    den += p0 + p1 + p2 + p3;
  }
  for (; e < end; e += 2){
    int s = csr[e];
    float p = __expf(leaky(a_s1[s*4+head] + ad));
    float4 v = *(const float4*)(h1 + (size_t)s*F1 + ch);
    ax += p*v.x; ay += p*v.y; az += p*v.z; aw += p*v.w; den += p;
  }
  ax += __shfl_xor(ax,32); ay += __shfl_xor(ay,32);
  az += __shfl_xor(az,32); aw += __shfl_xor(aw,32);
  den += __shfl_xor(den,32);
  if (sub == 0){
    float inv = 1.f/den;
    float4 bv = *(const float4*)(b1 + ch);
    float o0 = elu(ax*inv + bv.x);
    float o1 = elu(ay*inv + bv.y);
    float o2 = elu(az*inv + bv.z);
    float o3 = elu(aw*inv + bv.w);
    *(float4*)(h1a + (size_t)n*F1 + ch) = make_float4(o0,o1,o2,o3);
  }
}

// ---------------- GEMM2: h2 = h1a @ W2, fused att coefficients ----------------
__global__ __launch_bounds__(256) void gemm2_kernel(const float* __restrict__ h1a, const float* __restrict__ W2,
    const float* __restrict__ att_src, const float* __restrict__ att_dst,
    float* __restrict__ h2, float* __restrict__ as2, float* __restrict__ ad2, int M){
  __shared__ float As[64*132];   // [row][k] pad 132
  __shared__ float Ws[128*32];   // [k][col]
  const int tid = threadIdx.x;
  const int cg = tid & 15;       // cols 2cg,2cg+1
  const int rg = tid >> 4;       // rows 4rg..4rg+3
  const int m0 = blockIdx.x*64;
  #pragma unroll
  for (int p = 0; p < 8; ++p){
    int i = tid + 256*p;
    int r = i >> 5, q = i & 31;
    int row = m0 + r;
    float4 v = make_float4(0.f,0.f,0.f,0.f);
    if (row < M) v = *(const float4*)(h1a + (size_t)row*F1 + 4*q);
    *(float4*)&As[r*132 + 4*q] = v;
  }
  #pragma unroll
  for (int p = 0; p < 4; ++p){
    int i = tid + 256*p;
    ((float4*)Ws)[i] = ((const float4*)W2)[i];
  }
  __syncthreads();
  float acc[4][2] = {};
  const float* a0p = &As[(4*rg+0)*132];
  const float* a1p = &As[(4*rg+1)*132];
  const float* a2p = &As[(4*rg+2)*132];
  const float* a3p = &As[(4*rg+3)*132];
  #pragma unroll 8
  for (int kk = 0; kk < 128; ++kk){
    float2 w = *(const float2*)&Ws[kk*32 + 2*cg];
    float a0 = a0p[kk], a1 = a1p[kk], a2 = a2p[kk], a3 = a3p[kk];
    acc[0][0]+=a0*w.x; acc[0][1]+=a0*w.y;
    acc[1][0]+=a1*w.x; acc[1][1]+=a1*w.y;
    acc[2][0]+=a2*w.x; acc[2][1]+=a2*w.y;
    acc[3][0]+=a3*w.x; acc[3][1]+=a3*w.y;
  }
  const float2 sv = *(const float2*)(att_src + 2*cg);
  const float2 dv = *(const float2*)(att_dst + 2*cg);
  #pragma unroll
  for (int i = 0; i < 4; ++i){
    int row = m0 + 4*rg + i;
    if (row < M){
      float2 o = make_float2(acc[i][0], acc[i][1]);
      *(float2*)(h2 + (size_t)row*HID + 2*cg) = o;
      float ps = o.x*sv.x + o.y*sv.y;
      float pd = o.x*dv.x + o.y*dv.y;
      ps += __shfl_xor(ps,1); ps += __shfl_xor(ps,2); ps += __shfl_xor(ps,4); ps += __shfl_xor(ps,8);
      pd += __shfl_xor(pd,1); pd += __shfl_xor(pd,2); pd += __shfl_xor(pd,4); pd += __shfl_xor(pd,8);
      if (cg == 0){ as2[row] = ps; ad2[row] = pd; }
    }
  }
}

// ---------------- Aggregation 2 + bias + elu + final linear ----------------
__global__ __launch_bounds__(256) void agg2_kernel(const float* __restrict__ h2, const float* __restrict__ as2,
    const float* __restrict__ ad2, const int* __restrict__ offs, const int* __restrict__ csr,
    const float* __restrict__ b2, const float* __restrict__ linw, const float* __restrict__ linb,
    float* __restrict__ out, int N){
  int n = blockIdx.x*4 + (threadIdx.x >> 6);
  if (n >= N) return;
  const int lane = threadIdx.x & 63;
  const int sub  = lane >> 3;       // edge subgroup 0..7
  const int cl   = lane & 7;        // channel-lane
  const int ch   = 4*cl;
  const float ad = ad2[n];
  float ax=0.f, ay=0.f, az=0.f, aw=0.f, den=0.f;
  if (sub == 0){ // self loop
    float p = __expf(leaky(as2[n] + ad));
    float4 hv = *(const float4*)(h2 + (size_t)n*HID + ch);
    ax = p*hv.x; ay = p*hv.y; az = p*hv.z; aw = p*hv.w; den = p;
  }
  const int beg = offs[n], end = offs[n+1];
  int e = beg + sub;
  for (; e + 8 < end; e += 16){
    int s0 = csr[e], s1 = csr[e+8];
    float p0 = __expf(leaky(as2[s0] + ad));
    float p1 = __expf(leaky(as2[s1] + ad));
    float4 v0 = *(const float4*)(h2 + (size_t)s0*HID + ch);
    float4 v1 = *(const float4*)(h2 + (size_t)s1*HID + ch);
    ax += p0*v0.x + p1*v1.x;
    ay += p0*v0.y + p1*v1.y;
    az += p0*v0.z + p1*v1.z;
    aw += p0*v0.w + p1*v1.w;
    den += p0 + p1;
  }
  for (; e < end; e += 8){
    int s = csr[e];
    float p = __expf(leaky(as2[s] + ad));
    float4 v = *(const float4*)(h2 + (size_t)s*HID + ch);
    ax += p*v.x; ay += p*v.y; az += p*v.z; aw += p*v.w; den += p;
  }
  #pragma unroll
  for (int off = 8; off < 64; off <<= 1){
    ax += __shfl_xor(ax,off); ay += __shfl_xor(ay,off);
    az += __shfl_xor(az,off); aw += __shfl_xor(aw,off);
    den += __shfl_xor(den,off);
  }
  float inv = 1.f/den;
  float o0 = elu(ax*inv + b2[ch+0]);
  float o1 = elu(ay*inv + b2[ch+1]);
  float o2 = elu(az*inv + b2[ch+2]);
  float o3 = elu(aw*inv + b2[ch+3]);
  float r0 = o0*linw[2*(ch+0)]   + o1*linw[2*(ch+1)]   + o2*linw[2*(ch+2)]   + o3*linw[2*(ch+3)];
  float r1 = o0*linw[2*(ch+0)+1] + o1*linw[2*(ch+1)+1] + o2*linw[2*(ch+2)+1] + o3*linw[2*(ch+3)+1];
  r0 += __shfl_xor(r0,1); r0 += __shfl_xor(r0,2); r0 += __shfl_xor(r0,4);
  r1 += __shfl_xor(r1,1); r1 += __shfl_xor(r1,2); r1 += __shfl_xor(r1,4);
  if (lane == 0){
    out[(size_t)n*2+0] = r0 + linb[0];
    out[(size_t)n*2+1] = r1 + linb[1];
  }
}

// ---------------- launch ----------------
extern "C" void kernel_launch(void* const* d_in, const int* in_sizes, int n_in,
                              void* d_out, int out_size, void* d_ws, size_t ws_size,
                              hipStream_t stream) {
  const float* x    = (const float*)d_in[0];
  const int*   ei   = (const int*)  d_in[1];
  const float* W1   = (const float*)d_in[2];
  const float* as1w = (const float*)d_in[3];
  const float* ad1w = (const float*)d_in[4];
  const float* b1   = (const float*)d_in[5];
  const float* W2   = (const float*)d_in[6];
  const float* as2w = (const float*)d_in[7];
  const float* ad2w = (const float*)d_in[8];
  const float* b2   = (const float*)d_in[9];
  const float* linw = (const float*)d_in[10];
  const float* linb = (const float*)d_in[11];
  float* out = (float*)d_out;

  const int N = in_sizes[0] / IN_DIM;   // 50000
  const int E = in_sizes[1] / 2;        // 800000

  char* ws = (char*)d_ws;
  auto alloc = [&](size_t bytes) -> char* {
    char* p = ws; ws += (bytes + 255) & ~(size_t)255; return p;
  };
  float* h1   = (float*)alloc((size_t)N*F1*4);
  float* h1a  = (float*)alloc((size_t)N*F1*4);
  float* h2   = (float*)alloc((size_t)N*HID*4);
  float* a_s1 = (float*)alloc((size_t)N*4*4);
  float* a_d1 = (float*)alloc((size_t)N*4*4);
  float* a_s2 = (float*)alloc((size_t)N*4);
  float* a_d2 = (float*)alloc((size_t)N*4);
  int* cnt    = (int*)alloc((size_t)N*4);
  int* offs   = (int*)alloc((size_t)(N+1)*4);
  int* cursor = (int*)alloc((size_t)N*4);
  int* psum   = (int*)alloc(1024);
  int* pexcl  = (int*)alloc(1024);
  int* csr    = (int*)alloc((size_t)E*4);
  // W1 bf16 hi/lo (2 x 64 KiB) aliased into cnt's 200 KiB region — cnt is dead
  // after offsets_kernel, and convw runs after scatter_kernel. Zero net ws growth.
  unsigned short* W1h = (unsigned short*)cnt;
  unsigned short* W1l = W1h + (size_t)IN_DIM*F1;

  const int* srcs = ei;       // edge_index[0]
  const int* dsts = ei + E;   // edge_index[1]
  const int NB = (N + 255)/256;

  hipMemsetAsync(cnt, 0, (size_t)N*4, stream);
  hist_kernel<<<(E+255)/256, 256, 0, stream>>>(dsts, cnt, E);
  blocksum_kernel<<<NB, 256, 0, stream>>>(cnt, psum, N);
  scanpart_kernel<<<1, 256, 0, stream>>>(psum, pexcl, NB);
  offsets_kernel<<<NB, 256, 0, stream>>>(cnt, pexcl, offs, cursor, N, E);
  scatter_kernel<<<(E+255)/256, 256, 0, stream>>>(srcs, dsts, cursor, csr, E);
  convw_kernel<<<(IN_DIM*F1)/256, 256, 0, stream>>>(W1, W1h, W1l);
  gemm1_kernel<<<(N+63)/64, 256, 0, stream>>>(x, W1h, W1l, as1w, ad1w, h1, a_s1, a_d1, N);
  agg1_kernel<<<(N+3)/4, 256, 0, stream>>>(h1, a_s1, a_d1, offs, csr, b1, h1a, N);
  gemm2_kernel<<<(N+63)/64, 256, 0, stream>>>(h1a, W2, as2w, ad2w, h2, a_s2, a_d2, N);
  agg2_kernel<<<(N+3)/4, 256, 0, stream>>>(h2, a_s2, a_d2, offs, csr, b2, linw, linb, out, N);
}

// Round 5
// 296.464 us; speedup vs baseline: 1.3669x; 1.0849x over previous
//
#include <hip/hip_runtime.h>

#define IN_DIM 256
#define HID 32
#define HEADS 4
#define F1 128   // HEADS*HID

static __device__ __forceinline__ float leaky(float x){ return x > 0.f ? x : 0.2f*x; }
static __device__ __forceinline__ float elu(float x){ return x > 0.f ? x : (__expf(x) - 1.f); }

// bf16 helpers (round-to-nearest-even)
static __device__ __forceinline__ unsigned short f2bf(float f){
  unsigned int u = __float_as_uint(f);
  u += 0x7FFFu + ((u >> 16) & 1u);
  return (unsigned short)(u >> 16);
}
static __device__ __forceinline__ float bf2f(unsigned short h){
  return __uint_as_float(((unsigned int)h) << 16);
}
static __device__ __forceinline__ unsigned int pack2(unsigned short a, unsigned short b){
  return (unsigned int)a | ((unsigned int)b << 16);
}
// unpack a u32 holding two packed bf16 (lo = even channel, hi = odd channel)
static __device__ __forceinline__ float bflo(unsigned int u){ return __uint_as_float(u << 16); }
static __device__ __forceinline__ float bfhi(unsigned int u){ return __uint_as_float(u & 0xFFFF0000u); }

// ---------------- CSR build ----------------
__global__ void hist_kernel(const int* __restrict__ dsts, int* __restrict__ cnt, int E){
  int i = blockIdx.x*blockDim.x + threadIdx.x;
  if (i < E) atomicAdd(&cnt[dsts[i]], 1);
}

__device__ __forceinline__ int block_excl_scan(int v, int tid, int* total){
  __shared__ int ws[8];
  int lane = tid & 63, w = tid >> 6;
  int incl = v;
  #pragma unroll
  for (int d = 1; d < 64; d <<= 1){ int o = __shfl_up(incl, d); if (lane >= d) incl += o; }
  if (lane == 63) ws[w] = incl;
  __syncthreads();
  if (tid == 0){ int s = 0; for (int i = 0; i < 4; ++i){ int t = ws[i]; ws[i] = s; s += t; } ws[4] = s; }
  __syncthreads();
  *total = ws[4];
  return ws[w] + incl - v;   // exclusive
}

__global__ __launch_bounds__(256) void blocksum_kernel(const int* __restrict__ cnt, int* __restrict__ psum, int N){
  int i = blockIdx.x*256 + threadIdx.x;
  int v = (i < N) ? cnt[i] : 0;
  int tot; block_excl_scan(v, threadIdx.x, &tot);
  if (threadIdx.x == 0) psum[blockIdx.x] = tot;
}

__global__ __launch_bounds__(256) void scanpart_kernel(const int* __restrict__ psum, int* __restrict__ pexcl, int NB){
  int v = (threadIdx.x < NB) ? psum[threadIdx.x] : 0;
  int tot; int e = block_excl_scan(v, threadIdx.x, &tot);
  if (threadIdx.x < NB) pexcl[threadIdx.x] = e;
}

__global__ __launch_bounds__(256) void offsets_kernel(const int* __restrict__ cnt, const int* __restrict__ pexcl,
    int* __restrict__ offs, int* __restrict__ cursor, int N, int E){
  int i = blockIdx.x*256 + threadIdx.x;
  int v = (i < N) ? cnt[i] : 0;
  int tot; int e = block_excl_scan(v, threadIdx.x, &tot);
  int o = pexcl[blockIdx.x] + e;
  if (i < N){ offs[i] = o; cursor[i] = o; }
  if (blockIdx.x == 0 && threadIdx.x == 0) offs[N] = E;
}

__global__ void scatter_kernel(const int* __restrict__ srcs, const int* __restrict__ dsts,
    int* __restrict__ cursor, int* __restrict__ csr, int E){
  int i = blockIdx.x*blockDim.x + threadIdx.x;
  if (i < E){ int pos = atomicAdd(&cursor[dsts[i]], 1); csr[pos] = srcs[i]; }
}

// ---------------- W1 convert: f32 [k][n] -> bf16 hi/lo transposed [n][k] ----------------
__global__ __launch_bounds__(256) void convw_kernel(const float* __restrict__ W1,
    unsigned short* __restrict__ Wh, unsigned short* __restrict__ Wl){
  int i = blockIdx.x*256 + threadIdx.x;      // 0..32767
  int n = i >> 8, k = i & 255;
  float w = W1[(size_t)k*F1 + n];
  unsigned short h = f2bf(w);
  Wh[i] = h;
  Wl[i] = f2bf(w - bf2f(h));
}

// ---------------- GEMM1 (MFMA bf16 split): h1(bf16) = x @ W1, fused att coefficients ----------------
typedef __attribute__((ext_vector_type(8))) short bf8_t;
typedef __attribute__((ext_vector_type(4))) float f4_t;

__global__ __launch_bounds__(256) void gemm1_kernel(const float* __restrict__ x,
    const unsigned short* __restrict__ Wh, const unsigned short* __restrict__ Wl,
    const float* __restrict__ att_src, const float* __restrict__ att_dst,
    unsigned short* __restrict__ h1b, float* __restrict__ as1, float* __restrict__ ad1, int M){
  __shared__ uint4 AhV[64][5], AlV[64][5];    // [row][k-chunk], 80B rows (2-way only = free)
  __shared__ uint4 BhV[128][5], BlV[128][5];  // [n][k-chunk]
  const int tid = threadIdx.x;
  const int m0 = blockIdx.x*64;
  const int wave = tid >> 6, lane = tid & 63;
  const int quad = lane >> 4, l16 = lane & 15;
  const int wr = (wave & 1)*32;    // wave row base
  const int wc = (wave >> 1)*64;   // wave col base
  f4_t acc[2][4];
  #pragma unroll
  for (int r = 0; r < 2; ++r)
    #pragma unroll
    for (int c = 0; c < 4; ++c)
      #pragma unroll
      for (int i = 0; i < 4; ++i) acc[r][c][i] = 0.f;

  const int ar = tid >> 2, akc = tid & 3;
  const bool aok = (m0 + ar) < M;
  const float* ap = x + (size_t)(m0 + ar)*IN_DIM + 8*akc;
  const int bn = tid >> 1, bkc = (tid & 1)*2;
  const unsigned short* bph = Wh + (size_t)bn*256 + 16*(tid & 1);
  const unsigned short* bpl = Wl + (size_t)bn*256 + 16*(tid & 1);

  for (int k0 = 0; k0 < IN_DIM; k0 += 32){
    float4 a0 = make_float4(0.f,0.f,0.f,0.f), a1 = a0;
    if (aok){ a0 = *(const float4*)(ap + k0); a1 = *(const float4*)(ap + k0 + 4); }
    float v[8] = {a0.x,a0.y,a0.z,a0.w,a1.x,a1.y,a1.z,a1.w};
    unsigned short hh[8], ll[8];
    #pragma unroll
    for (int j = 0; j < 8; ++j){
      unsigned short h = f2bf(v[j]); hh[j] = h; ll[j] = f2bf(v[j] - bf2f(h));
    }
    uint4 hv; hv.x = pack2(hh[0],hh[1]); hv.y = pack2(hh[2],hh[3]); hv.z = pack2(hh[4],hh[5]); hv.w = pack2(hh[6],hh[7]);
    uint4 lv; lv.x = pack2(ll[0],ll[1]); lv.y = pack2(ll[2],ll[3]); lv.z = pack2(ll[4],ll[5]); lv.w = pack2(ll[6],ll[7]);
    AhV[ar][akc] = hv;
    AlV[ar][akc] = lv;
    BhV[bn][bkc+0] = *(const uint4*)(bph + k0);
    BhV[bn][bkc+1] = *(const uint4*)(bph + k0 + 8);
    BlV[bn][bkc+0] = *(const uint4*)(bpl + k0);
    BlV[bn][bkc+1] = *(const uint4*)(bpl + k0 + 8);
    __syncthreads();

    bf8_t arh[2], arl[2], brh[4], brl[4];
    #pragma unroll
    for (int r = 0; r < 2; ++r){
      arh[r] = *(const bf8_t*)&AhV[wr + r*16 + l16][quad];
      arl[r] = *(const bf8_t*)&AlV[wr + r*16 + l16][quad];
    }
    #pragma unroll
    for (int c = 0; c < 4; ++c){
      brh[c] = *(const bf8_t*)&BhV[wc + c*16 + l16][quad];
      brl[c] = *(const bf8_t*)&BlV[wc + c*16 + l16][quad];
    }
    #pragma unroll
    for (int r = 0; r < 2; ++r)
      #pragma unroll
      for (int c = 0; c < 4; ++c){
        acc[r][c] = __builtin_amdgcn_mfma_f32_16x16x32_bf16(arh[r], brh[c], acc[r][c], 0, 0, 0);
        acc[r][c] = __builtin_amdgcn_mfma_f32_16x16x32_bf16(arh[r], brl[c], acc[r][c], 0, 0, 0);
        acc[r][c] = __builtin_amdgcn_mfma_f32_16x16x32_bf16(arl[r], brh[c], acc[r][c], 0, 0, 0);
      }
    __syncthreads();
  }

  // epilogue: C/D layout col = l16, row = quad*4 + i; h1 stored as bf16
  const int head0 = wc >> 5;
  float sv[4], dv[4];
  #pragma unroll
  for (int c = 0; c < 4; ++c){
    int col_in_head = (c & 1)*16 + l16;
    sv[c] = att_src[(head0 + (c >> 1))*HID + col_in_head];
    dv[c] = att_dst[(head0 + (c >> 1))*HID + col_in_head];
  }
  #pragma unroll
  for (int r = 0; r < 2; ++r){
    #pragma unroll
    for (int i = 0; i < 4; ++i){
      int row = m0 + wr + r*16 + quad*4 + i;
      bool ok = row < M;
      float hv0 = acc[r][0][i], hv1 = acc[r][1][i], hv2 = acc[r][2][i], hv3 = acc[r][3][i];
      if (ok){
        unsigned short* hp = h1b + (size_t)row*F1 + wc + l16;
        hp[0]  = f2bf(hv0); hp[16] = f2bf(hv1); hp[32] = f2bf(hv2); hp[48] = f2bf(hv3);
      }
      float p0 = hv0*sv[0] + hv1*sv[1];
      float p1 = hv2*sv[2] + hv3*sv[3];
      float q0 = hv0*dv[0] + hv1*dv[1];
      float q1 = hv2*dv[2] + hv3*dv[3];
      p0 += __shfl_xor(p0,1); p0 += __shfl_xor(p0,2); p0 += __shfl_xor(p0,4); p0 += __shfl_xor(p0,8);
      p1 += __shfl_xor(p1,1); p1 += __shfl_xor(p1,2); p1 += __shfl_xor(p1,4); p1 += __shfl_xor(p1,8);
      q0 += __shfl_xor(q0,1); q0 += __shfl_xor(q0,2); q0 += __shfl_xor(q0,4); q0 += __shfl_xor(q0,8);
      q1 += __shfl_xor(q1,1); q1 += __shfl_xor(q1,2); q1 += __shfl_xor(q1,4); q1 += __shfl_xor(q1,8);
      if (ok && l16 == 0){
        as1[row*4 + head0]     = p0;
        as1[row*4 + head0 + 1] = p1;
        ad1[row*4 + head0]     = q0;
        ad1[row*4 + head0 + 1] = q1;
      }
    }
  }
}

// ---------------- Aggregation 1 (bf16 h1 gather) ----------------
// One wave per node; 4 edge-subgroups x 16 lanes; lane holds 8 bf16 channels (uint4/edge).
// 4-edge unroll per subgroup -> up to 16 gather rows in flight per wave.
__global__ __launch_bounds__(256) void agg1_kernel(const unsigned int* __restrict__ h1b,
    const float* __restrict__ a_s1, const float* __restrict__ a_d1,
    const int* __restrict__ offs, const int* __restrict__ csr,
    const float* __restrict__ b1, float* __restrict__ h1a, int N){
  int n = blockIdx.x*4 + (threadIdx.x >> 6);
  if (n >= N) return;
  const int lane = threadIdx.x & 63;
  const int sub  = lane >> 4;       // edge subgroup 0..3
  const int cl   = lane & 15;       // channel-lane
  const int head = cl >> 2;         // 8 channels per lane, 32 per head
  const float ad = a_d1[n*4+head];
  // h1b viewed as u32: 64 u32 per row; lane reads 4 u32 = 8 bf16 channels
  const int cw = 4*cl;              // u32 offset within row
  float a0=0,a1=0,a2=0,a3=0,a4=0,a5=0,a6=0,a7=0,den=0;
  if (sub == 0){ // self loop
    float p = __expf(leaky(a_s1[n*4+head] + ad));
    uint4 u = *(const uint4*)(h1b + (size_t)n*64 + cw);
    a0 = p*bflo(u.x); a1 = p*bfhi(u.x); a2 = p*bflo(u.y); a3 = p*bfhi(u.y);
    a4 = p*bflo(u.z); a5 = p*bfhi(u.z); a6 = p*bflo(u.w); a7 = p*bfhi(u.w);
    den = p;
  }
  const int beg = offs[n], end = offs[n+1];
  int e = beg + sub;
  for (; e + 12 < end; e += 16){
    int s0 = csr[e], s1 = csr[e+4], s2 = csr[e+8], s3 = csr[e+12];
    float p0 = __expf(leaky(a_s1[s0*4+head] + ad));
    float p1 = __expf(leaky(a_s1[s1*4+head] + ad));
    float p2 = __expf(leaky(a_s1[s2*4+head] + ad));
    float p3 = __expf(leaky(a_s1[s3*4+head] + ad));
    uint4 u0 = *(const uint4*)(h1b + (size_t)s0*64 + cw);
    uint4 u1 = *(const uint4*)(h1b + (size_t)s1*64 + cw);
    uint4 u2 = *(const uint4*)(h1b + (size_t)s2*64 + cw);
    uint4 u3 = *(const uint4*)(h1b + (size_t)s3*64 + cw);
    a0 += p0*bflo(u0.x) + p1*bflo(u1.x) + p2*bflo(u2.x) + p3*bflo(u3.x);
    a1 += p0*bfhi(u0.x) + p1*bfhi(u1.x) + p2*bfhi(u2.x) + p3*bfhi(u3.x);
    a2 += p0*bflo(u0.y) + p1*bflo(u1.y) + p2*bflo(u2.y) + p3*bflo(u3.y);
    a3 += p0*bfhi(u0.y) + p1*bfhi(u1.y) + p2*bfhi(u2.y) + p3*bfhi(u3.y);
    a4 += p0*bflo(u0.z) + p1*bflo(u1.z) + p2*bflo(u2.z) + p3*bflo(u3.z);
    a5 += p0*bfhi(u0.z) + p1*bfhi(u1.z) + p2*bfhi(u2.z) + p3*bfhi(u3.z);
    a6 += p0*bflo(u0.w) + p1*bflo(u1.w) + p2*bflo(u2.w) + p3*bflo(u3.w);
    a7 += p0*bfhi(u0.w) + p1*bfhi(u1.w) + p2*bfhi(u2.w) + p3*bfhi(u3.w);
    den += p0 + p1 + p2 + p3;
  }
  for (; e < end; e += 4){
    int s = csr[e];
    float p = __expf(leaky(a_s1[s*4+head] + ad));
    uint4 u = *(const uint4*)(h1b + (size_t)s*64 + cw);
    a0 += p*bflo(u.x); a1 += p*bfhi(u.x); a2 += p*bflo(u.y); a3 += p*bfhi(u.y);
    a4 += p*bflo(u.z); a5 += p*bfhi(u.z); a6 += p*bflo(u.w); a7 += p*bfhi(u.w);
    den += p;
  }
  // combine the four subgroups
  #pragma unroll
  for (int off = 16; off < 64; off <<= 1){
    a0 += __shfl_xor(a0,off); a1 += __shfl_xor(a1,off);
    a2 += __shfl_xor(a2,off); a3 += __shfl_xor(a3,off);
    a4 += __shfl_xor(a4,off); a5 += __shfl_xor(a5,off);
    a6 += __shfl_xor(a6,off); a7 += __shfl_xor(a7,off);
    den += __shfl_xor(den,off);
  }
  if (sub == 0){
    float inv = 1.f/den;
    int ch = 8*cl;
    float4 b0 = *(const float4*)(b1 + ch);
    float4 b4 = *(const float4*)(b1 + ch + 4);
    float4 o0 = make_float4(elu(a0*inv+b0.x), elu(a1*inv+b0.y), elu(a2*inv+b0.z), elu(a3*inv+b0.w));
    float4 o4 = make_float4(elu(a4*inv+b4.x), elu(a5*inv+b4.y), elu(a6*inv+b4.z), elu(a7*inv+b4.w));
    *(float4*)(h1a + (size_t)n*F1 + ch)     = o0;
    *(float4*)(h1a + (size_t)n*F1 + ch + 4) = o4;
  }
}

// ---------------- GEMM2: h2(bf16) = h1a @ W2, fused att coefficients ----------------
__global__ __launch_bounds__(256) void gemm2_kernel(const float* __restrict__ h1a, const float* __restrict__ W2,
    const float* __restrict__ att_src, const float* __restrict__ att_dst,
    unsigned int* __restrict__ h2b, float* __restrict__ as2, float* __restrict__ ad2, int M){
  __shared__ float As[64*132];   // [row][k] pad 132
  __shared__ float Ws[128*32];   // [k][col]
  const int tid = threadIdx.x;
  const int cg = tid & 15;       // cols 2cg,2cg+1
  const int rg = tid >> 4;       // rows 4rg..4rg+3
  const int m0 = blockIdx.x*64;
  #pragma unroll
  for (int p = 0; p < 8; ++p){
    int i = tid + 256*p;
    int r = i >> 5, q = i & 31;
    int row = m0 + r;
    float4 v = make_float4(0.f,0.f,0.f,0.f);
    if (row < M) v = *(const float4*)(h1a + (size_t)row*F1 + 4*q);
    *(float4*)&As[r*132 + 4*q] = v;
  }
  #pragma unroll
  for (int p = 0; p < 4; ++p){
    int i = tid + 256*p;
    ((float4*)Ws)[i] = ((const float4*)W2)[i];
  }
  __syncthreads();
  float acc[4][2] = {};
  const float* a0p = &As[(4*rg+0)*132];
  const float* a1p = &As[(4*rg+1)*132];
  const float* a2p = &As[(4*rg+2)*132];
  const float* a3p = &As[(4*rg+3)*132];
  #pragma unroll 8
  for (int kk = 0; kk < 128; ++kk){
    float2 w = *(const float2*)&Ws[kk*32 + 2*cg];
    float a0 = a0p[kk], a1 = a1p[kk], a2 = a2p[kk], a3 = a3p[kk];
    acc[0][0]+=a0*w.x; acc[0][1]+=a0*w.y;
    acc[1][0]+=a1*w.x; acc[1][1]+=a1*w.y;
    acc[2][0]+=a2*w.x; acc[2][1]+=a2*w.y;
    acc[3][0]+=a3*w.x; acc[3][1]+=a3*w.y;
  }
  const float2 sv = *(const float2*)(att_src + 2*cg);
  const float2 dv = *(const float2*)(att_dst + 2*cg);
  #pragma unroll
  for (int i = 0; i < 4; ++i){
    int row = m0 + 4*rg + i;
    if (row < M){
      float2 o = make_float2(acc[i][0], acc[i][1]);
      h2b[(size_t)row*16 + cg] = pack2(f2bf(o.x), f2bf(o.y));
      float ps = o.x*sv.x + o.y*sv.y;
      float pd = o.x*dv.x + o.y*dv.y;
      ps += __shfl_xor(ps,1); ps += __shfl_xor(ps,2); ps += __shfl_xor(ps,4); ps += __shfl_xor(ps,8);
      pd += __shfl_xor(pd,1); pd += __shfl_xor(pd,2); pd += __shfl_xor(pd,4); pd += __shfl_xor(pd,8);
      if (cg == 0){ as2[row] = ps; ad2[row] = pd; }
    }
  }
}

// ---------------- Aggregation 2 + bias + elu + final linear (bf16 h2 gather) ----------------
// One wave per node; 8 edge-subgroups x 8 lanes; lane holds 4 bf16 channels (uint2/edge).
__global__ __launch_bounds__(256) void agg2_kernel(const unsigned int* __restrict__ h2b,
    const float* __restrict__ as2, const float* __restrict__ ad2,
    const int* __restrict__ offs, const int* __restrict__ csr,
    const float* __restrict__ b2, const float* __restrict__ linw, const float* __restrict__ linb,
    float* __restrict__ out, int N){
  int n = blockIdx.x*4 + (threadIdx.x >> 6);
  if (n >= N) return;
  const int lane = threadIdx.x & 63;
  const int sub  = lane >> 3;       // edge subgroup 0..7
  const int cl   = lane & 7;        // channel-lane
  const int cw   = 2*cl;            // u32 offset within 16-u32 row
  const float ad = ad2[n];
  float a0=0,a1=0,a2=0,a3=0,den=0;
  if (sub == 0){ // self loop
    float p = __expf(leaky(as2[n] + ad));
    uint2 u = *(const uint2*)(h2b + (size_t)n*16 + cw);
    a0 = p*bflo(u.x); a1 = p*bfhi(u.x); a2 = p*bflo(u.y); a3 = p*bfhi(u.y);
    den = p;
  }
  const int beg = offs[n], end = offs[n+1];
  int e = beg + sub;
  for (; e + 8 < end; e += 16){
    int s0 = csr[e], s1 = csr[e+8];
    float p0 = __expf(leaky(as2[s0] + ad));
    float p1 = __expf(leaky(as2[s1] + ad));
    uint2 u0 = *(const uint2*)(h2b + (size_t)s0*16 + cw);
    uint2 u1 = *(const uint2*)(h2b + (size_t)s1*16 + cw);
    a0 += p0*bflo(u0.x) + p1*bflo(u1.x);
    a1 += p0*bfhi(u0.x) + p1*bfhi(u1.x);
    a2 += p0*bflo(u0.y) + p1*bflo(u1.y);
    a3 += p0*bfhi(u0.y) + p1*bfhi(u1.y);
    den += p0 + p1;
  }
  for (; e < end; e += 8){
    int s = csr[e];
    float p = __expf(leaky(as2[s] + ad));
    uint2 u = *(const uint2*)(h2b + (size_t)s*16 + cw);
    a0 += p*bflo(u.x); a1 += p*bfhi(u.x); a2 += p*bflo(u.y); a3 += p*bfhi(u.y);
    den += p;
  }
  #pragma unroll
  for (int off = 8; off < 64; off <<= 1){
    a0 += __shfl_xor(a0,off); a1 += __shfl_xor(a1,off);
    a2 += __shfl_xor(a2,off); a3 += __shfl_xor(a3,off);
    den += __shfl_xor(den,off);
  }
  float inv = 1.f/den;
  int ch = 4*cl;
  float o0 = elu(a0*inv + b2[ch+0]);
  float o1 = elu(a1*inv + b2[ch+1]);
  float o2 = elu(a2*inv + b2[ch+2]);
  float o3 = elu(a3*inv + b2[ch+3]);
  float r0 = o0*linw[2*(ch+0)]   + o1*linw[2*(ch+1)]   + o2*linw[2*(ch+2)]   + o3*linw[2*(ch+3)];
  float r1 = o0*linw[2*(ch+0)+1] + o1*linw[2*(ch+1)+1] + o2*linw[2*(ch+2)+1] + o3*linw[2*(ch+3)+1];
  r0 += __shfl_xor(r0,1); r0 += __shfl_xor(r0,2); r0 += __shfl_xor(r0,4);
  r1 += __shfl_xor(r1,1); r1 += __shfl_xor(r1,2); r1 += __shfl_xor(r1,4);
  if (lane == 0){
    out[(size_t)n*2+0] = r0 + linb[0];
    out[(size_t)n*2+1] = r1 + linb[1];
  }
}

// ---------------- launch ----------------
extern "C" void kernel_launch(void* const* d_in, const int* in_sizes, int n_in,
                              void* d_out, int out_size, void* d_ws, size_t ws_size,
                              hipStream_t stream) {
  const float* x    = (const float*)d_in[0];
  const int*   ei   = (const int*)  d_in[1];
  const float* W1   = (const float*)d_in[2];
  const float* as1w = (const float*)d_in[3];
  const float* ad1w = (const float*)d_in[4];
  const float* b1   = (const float*)d_in[5];
  const float* W2   = (const float*)d_in[6];
  const float* as2w = (const float*)d_in[7];
  const float* ad2w = (const float*)d_in[8];
  const float* b2   = (const float*)d_in[9];
  const float* linw = (const float*)d_in[10];
  const float* linb = (const float*)d_in[11];
  float* out = (float*)d_out;

  const int N = in_sizes[0] / IN_DIM;   // 50000
  const int E = in_sizes[1] / 2;        // 800000

  char* ws = (char*)d_ws;
  auto alloc = [&](size_t bytes) -> char* {
    char* p = ws; ws += (bytes + 255) & ~(size_t)255; return p;
  };
  unsigned short* h1b = (unsigned short*)alloc((size_t)N*F1*2);  // bf16
  float* h1a  = (float*)alloc((size_t)N*F1*4);
  unsigned int* h2b = (unsigned int*)alloc((size_t)N*HID*2);     // bf16 packed
  float* a_s1 = (float*)alloc((size_t)N*4*4);
  float* a_d1 = (float*)alloc((size_t)N*4*4);
  float* a_s2 = (float*)alloc((size_t)N*4);
  float* a_d2 = (float*)alloc((size_t)N*4);
  int* cnt    = (int*)alloc((size_t)N*4);
  int* offs   = (int*)alloc((size_t)(N+1)*4);
  int* cursor = (int*)alloc((size_t)N*4);
  int* psum   = (int*)alloc(1024);
  int* pexcl  = (int*)alloc(1024);
  int* csr    = (int*)alloc((size_t)E*4);
  // W1 bf16 hi/lo aliased into cnt's region (dead after offsets_kernel)
  unsigned short* W1h = (unsigned short*)cnt;
  unsigned short* W1l = W1h + (size_t)IN_DIM*F1;

  const int* srcs = ei;       // edge_index[0]
  const int* dsts = ei + E;   // edge_index[1]
  const int NB = (N + 255)/256;

  hipMemsetAsync(cnt, 0, (size_t)N*4, stream);
  hist_kernel<<<(E+255)/256, 256, 0, stream>>>(dsts, cnt, E);
  blocksum_kernel<<<NB, 256, 0, stream>>>(cnt, psum, N);
  scanpart_kernel<<<1, 256, 0, stream>>>(psum, pexcl, NB);
  offsets_kernel<<<NB, 256, 0, stream>>>(cnt, pexcl, offs, cursor, N, E);
  scatter_kernel<<<(E+255)/256, 256, 0, stream>>>(srcs, dsts, cursor, csr, E);
  convw_kernel<<<(IN_DIM*F1)/256, 256, 0, stream>>>(W1, W1h, W1l);
  gemm1_kernel<<<(N+63)/64, 256, 0, stream>>>(x, W1h, W1l, as1w, ad1w, h1b, a_s1, a_d1, N);
  agg1_kernel<<<(N+3)/4, 256, 0, stream>>>((const unsigned int*)h1b, a_s1, a_d1, offs, csr, b1, h1a, N);
  gemm2_kernel<<<(N+63)/64, 256, 0, stream>>>(h1a, W2, as2w, ad2w, h2b, a_s2, a_d2, N);
  agg2_kernel<<<(N+3)/4, 256, 0, stream>>>(h2b, a_s2, a_d2, offs, csr, b2, linw, linb, out, N);
}

// Round 6
// 240.267 us; speedup vs baseline: 1.6866x; 1.2339x over previous
//
#include <hip/hip_runtime.h>

#define IN_DIM 256
#define HID 32
#define HEADS 4
#define F1 128   // HEADS*HID
#define BSHIFT 9           // 512 nodes per coarse bucket
#define MAXBUK 128         // LDS sizing (actual nbuk = 98 for N=50000)

static __device__ __forceinline__ float leaky(float x){ return x > 0.f ? x : 0.2f*x; }
static __device__ __forceinline__ float elu(float x){ return x > 0.f ? x : (__expf(x) - 1.f); }

// bf16 helpers (round-to-nearest-even)
static __device__ __forceinline__ unsigned short f2bf(float f){
  unsigned int u = __float_as_uint(f);
  u += 0x7FFFu + ((u >> 16) & 1u);
  return (unsigned short)(u >> 16);
}
static __device__ __forceinline__ float bf2f(unsigned short h){
  return __uint_as_float(((unsigned int)h) << 16);
}
static __device__ __forceinline__ unsigned int pack2(unsigned short a, unsigned short b){
  return (unsigned int)a | ((unsigned int)b << 16);
}
static __device__ __forceinline__ float bflo(unsigned int u){ return __uint_as_float(u << 16); }
static __device__ __forceinline__ float bfhi(unsigned int u){ return __uint_as_float(u & 0xFFFF0000u); }

__device__ __forceinline__ int block_excl_scan(int v, int tid, int* total){
  __shared__ int ws[8];
  int lane = tid & 63, w = tid >> 6;
  int incl = v;
  #pragma unroll
  for (int d = 1; d < 64; d <<= 1){ int o = __shfl_up(incl, d); if (lane >= d) incl += o; }
  if (lane == 63) ws[w] = incl;
  __syncthreads();
  if (tid == 0){ int s = 0; for (int i = 0; i < 4; ++i){ int t = ws[i]; ws[i] = s; s += t; } ws[4] = s; }
  __syncthreads();
  *total = ws[4];
  int e = ws[w] + incl - v;   // exclusive
  __syncthreads();            // allow reuse of ws in loops
  return e;
}

// ---------------- CSR build: deterministic two-level bucket sort ----------------
// passA: per-chunk coarse-bucket counts (LDS-aggregated, no global atomics)
__global__ __launch_bounds__(256) void bukcnt_kernel(const int* __restrict__ dsts,
    int* __restrict__ cnt_blk, int E, int nbuk, int stride){
  __shared__ int lcnt[MAXBUK];
  int tid = threadIdx.x, blk = blockIdx.x;
  if (tid < nbuk) lcnt[tid] = 0;
  __syncthreads();
  int base = blk*2048;
  #pragma unroll
  for (int j = 0; j < 8; ++j){
    int i = base + tid + j*256;
    if (i < E) atomicAdd(&lcnt[dsts[i] >> BSHIFT], 1);
  }
  __syncthreads();
  if (tid < nbuk) cnt_blk[tid*stride + blk] = lcnt[tid];
}

// S1: per-bucket exclusive scan over chunks (in-place), bucket totals out
__global__ __launch_bounds__(256) void bukscan1_kernel(int* __restrict__ cnt_blk,
    int* __restrict__ btot, int nchk, int stride){
  int b = blockIdx.x, tid = threadIdx.x;
  int carry = 0;
  for (int s = 0; s < nchk; s += 256){
    int i = s + tid;
    int v = (i < nchk) ? cnt_blk[b*stride + i] : 0;
    int tot; int e = block_excl_scan(v, tid, &tot);
    if (i < nchk) cnt_blk[b*stride + i] = carry + e;
    carry += tot;
  }
  if (tid == 0) btot[b] = carry;
}

// S2: scan bucket totals -> bucket_base[0..nbuk]; also offs[N] = E
__global__ __launch_bounds__(256) void bukscan2_kernel(const int* __restrict__ btot,
    int* __restrict__ bucket_base, int* __restrict__ offs, int nbuk, int Nn, int E){
  int tid = threadIdx.x;
  int v = (tid < nbuk) ? btot[tid] : 0;
  int tot; int e = block_excl_scan(v, tid, &tot);
  if (tid <= nbuk) bucket_base[tid] = e;
  if (tid == 0) offs[Nn] = E;
}

// passB: scatter (src,dst) into bucket-sorted intermediate; deterministic slices, LDS cursors only
__global__ __launch_bounds__(256) void bukscat_kernel(const int* __restrict__ srcs,
    const int* __restrict__ dsts, const int* __restrict__ cnt_blk,
    const int* __restrict__ bucket_base, uint2* __restrict__ im,
    int E, int nbuk, int stride){
  __shared__ int lcur[MAXBUK];
  int tid = threadIdx.x, blk = blockIdx.x;
  if (tid < nbuk) lcur[tid] = bucket_base[tid] + cnt_blk[tid*stride + blk];
  __syncthreads();
  int base = blk*2048;
  #pragma unroll
  for (int j = 0; j < 8; ++j){
    int i = base + tid + j*256;
    if (i < E){
      int s = srcs[i], d = dsts[i];
      int r = atomicAdd(&lcur[d >> BSHIFT], 1);
      im[r] = make_uint2((unsigned)s, (unsigned)d);
    }
  }
}

// passC: per-bucket fine sort (per-node hist + scan + scatter, all LDS); csr window is contiguous
__global__ __launch_bounds__(256) void bukfine_kernel(const uint2* __restrict__ im,
    const int* __restrict__ bucket_base, int* __restrict__ offs, int* __restrict__ csr, int Nn){
  __shared__ int lcnt[512], lpfx[512];
  int b = blockIdx.x, tid = threadIdx.x;
  int node0 = b << BSHIFT;
  int nn = min(512, Nn - node0);
  lcnt[tid] = 0; lcnt[tid+256] = 0;
  __syncthreads();
  int ebeg = bucket_base[b], eend = bucket_base[b+1];
  for (int i = ebeg + tid; i < eend; i += 256)
    atomicAdd(&lcnt[(int)im[i].y - node0], 1);
  __syncthreads();
  int carry = 0;
  for (int s = 0; s < 512; s += 256){
    int v = lcnt[s + tid];
    int tot; int e = block_excl_scan(v, tid, &tot);
    lpfx[s + tid] = carry + e;
    carry += tot;
  }
  __syncthreads();
  if (tid < nn) offs[node0 + tid] = ebeg + lpfx[tid];
  if (tid + 256 < nn) offs[node0 + tid + 256] = ebeg + lpfx[tid + 256];
  lcnt[tid] = ebeg + lpfx[tid];
  lcnt[tid+256] = ebeg + lpfx[tid+256];
  __syncthreads();
  for (int i = ebeg + tid; i < eend; i += 256){
    uint2 u = im[i];
    int pos = atomicAdd(&lcnt[(int)u.y - node0], 1);
    csr[pos] = (int)u.x;
  }
}

// ---------------- W1 convert: f32 [k][n] -> bf16 hi/lo transposed [n][k] ----------------
__global__ __launch_bounds__(256) void convw_kernel(const float* __restrict__ W1,
    unsigned short* __restrict__ Wh, unsigned short* __restrict__ Wl){
  int i = blockIdx.x*256 + threadIdx.x;      // 0..32767
  int n = i >> 8, k = i & 255;
  float w = W1[(size_t)k*F1 + n];
  unsigned short h = f2bf(w);
  Wh[i] = h;
  Wl[i] = f2bf(w - bf2f(h));
}

// ---------------- GEMM1 (MFMA bf16 split): h1(bf16) = x @ W1, fused att coefficients ----------------
typedef __attribute__((ext_vector_type(8))) short bf8_t;
typedef __attribute__((ext_vector_type(4))) float f4_t;

__global__ __launch_bounds__(256) void gemm1_kernel(const float* __restrict__ x,
    const unsigned short* __restrict__ Wh, const unsigned short* __restrict__ Wl,
    const float* __restrict__ att_src, const float* __restrict__ att_dst,
    unsigned short* __restrict__ h1b, float* __restrict__ as1, float* __restrict__ ad1, int M){
  __shared__ uint4 AhV[64][5], AlV[64][5];    // [row][k-chunk], 80B rows (2-way only = free)
  __shared__ uint4 BhV[128][5], BlV[128][5];  // [n][k-chunk]
  const int tid = threadIdx.x;
  const int m0 = blockIdx.x*64;
  const int wave = tid >> 6, lane = tid & 63;
  const int quad = lane >> 4, l16 = lane & 15;
  const int wr = (wave & 1)*32;
  const int wc = (wave >> 1)*64;
  f4_t acc[2][4];
  #pragma unroll
  for (int r = 0; r < 2; ++r)
    #pragma unroll
    for (int c = 0; c < 4; ++c)
      #pragma unroll
      for (int i = 0; i < 4; ++i) acc[r][c][i] = 0.f;

  const int ar = tid >> 2, akc = tid & 3;
  const bool aok = (m0 + ar) < M;
  const float* ap = x + (size_t)(m0 + ar)*IN_DIM + 8*akc;
  const int bn = tid >> 1, bkc = (tid & 1)*2;
  const unsigned short* bph = Wh + (size_t)bn*256 + 16*(tid & 1);
  const unsigned short* bpl = Wl + (size_t)bn*256 + 16*(tid & 1);

  for (int k0 = 0; k0 < IN_DIM; k0 += 32){
    float4 a0 = make_float4(0.f,0.f,0.f,0.f), a1 = a0;
    if (aok){ a0 = *(const float4*)(ap + k0); a1 = *(const float4*)(ap + k0 + 4); }
    float v[8] = {a0.x,a0.y,a0.z,a0.w,a1.x,a1.y,a1.z,a1.w};
    unsigned short hh[8], ll[8];
    #pragma unroll
    for (int j = 0; j < 8; ++j){
      unsigned short h = f2bf(v[j]); hh[j] = h; ll[j] = f2bf(v[j] - bf2f(h));
    }
    uint4 hv; hv.x = pack2(hh[0],hh[1]); hv.y = pack2(hh[2],hh[3]); hv.z = pack2(hh[4],hh[5]); hv.w = pack2(hh[6],hh[7]);
    uint4 lv; lv.x = pack2(ll[0],ll[1]); lv.y = pack2(ll[2],ll[3]); lv.z = pack2(ll[4],ll[5]); lv.w = pack2(ll[6],ll[7]);
    AhV[ar][akc] = hv;
    AlV[ar][akc] = lv;
    BhV[bn][bkc+0] = *(const uint4*)(bph + k0);
    BhV[bn][bkc+1] = *(const uint4*)(bph + k0 + 8);
    BlV[bn][bkc+0] = *(const uint4*)(bpl + k0);
    BlV[bn][bkc+1] = *(const uint4*)(bpl + k0 + 8);
    __syncthreads();

    bf8_t arh[2], arl[2], brh[4], brl[4];
    #pragma unroll
    for (int r = 0; r < 2; ++r){
      arh[r] = *(const bf8_t*)&AhV[wr + r*16 + l16][quad];
      arl[r] = *(const bf8_t*)&AlV[wr + r*16 + l16][quad];
    }
    #pragma unroll
    for (int c = 0; c < 4; ++c){
      brh[c] = *(const bf8_t*)&BhV[wc + c*16 + l16][quad];
      brl[c] = *(const bf8_t*)&BlV[wc + c*16 + l16][quad];
    }
    #pragma unroll
    for (int r = 0; r < 2; ++r)
      #pragma unroll
      for (int c = 0; c < 4; ++c){
        acc[r][c] = __builtin_amdgcn_mfma_f32_16x16x32_bf16(arh[r], brh[c], acc[r][c], 0, 0, 0);
        acc[r][c] = __builtin_amdgcn_mfma_f32_16x16x32_bf16(arh[r], brl[c], acc[r][c], 0, 0, 0);
        acc[r][c] = __builtin_amdgcn_mfma_f32_16x16x32_bf16(arl[r], brh[c], acc[r][c], 0, 0, 0);
      }
    __syncthreads();
  }

  const int head0 = wc >> 5;
  float sv[4], dv[4];
  #pragma unroll
  for (int c = 0; c < 4; ++c){
    int col_in_head = (c & 1)*16 + l16;
    sv[c] = att_src[(head0 + (c >> 1))*HID + col_in_head];
    dv[c] = att_dst[(head0 + (c >> 1))*HID + col_in_head];
  }
  #pragma unroll
  for (int r = 0; r < 2; ++r){
    #pragma unroll
    for (int i = 0; i < 4; ++i){
      int row = m0 + wr + r*16 + quad*4 + i;
      bool ok = row < M;
      float hv0 = acc[r][0][i], hv1 = acc[r][1][i], hv2 = acc[r][2][i], hv3 = acc[r][3][i];
      if (ok){
        unsigned short* hp = h1b + (size_t)row*F1 + wc + l16;
        hp[0]  = f2bf(hv0); hp[16] = f2bf(hv1); hp[32] = f2bf(hv2); hp[48] = f2bf(hv3);
      }
      float p0 = hv0*sv[0] + hv1*sv[1];
      float p1 = hv2*sv[2] + hv3*sv[3];
      float q0 = hv0*dv[0] + hv1*dv[1];
      float q1 = hv2*dv[2] + hv3*dv[3];
      p0 += __shfl_xor(p0,1); p0 += __shfl_xor(p0,2); p0 += __shfl_xor(p0,4); p0 += __shfl_xor(p0,8);
      p1 += __shfl_xor(p1,1); p1 += __shfl_xor(p1,2); p1 += __shfl_xor(p1,4); p1 += __shfl_xor(p1,8);
      q0 += __shfl_xor(q0,1); q0 += __shfl_xor(q0,2); q0 += __shfl_xor(q0,4); q0 += __shfl_xor(q0,8);
      q1 += __shfl_xor(q1,1); q1 += __shfl_xor(q1,2); q1 += __shfl_xor(q1,4); q1 += __shfl_xor(q1,8);
      if (ok && l16 == 0){
        as1[row*4 + head0]     = p0;
        as1[row*4 + head0 + 1] = p1;
        ad1[row*4 + head0]     = q0;
        ad1[row*4 + head0 + 1] = q1;
      }
    }
  }
}

// ---------------- Aggregation 1 (bf16 h1 gather) ----------------
__global__ __launch_bounds__(256) void agg1_kernel(const unsigned int* __restrict__ h1b,
    const float* __restrict__ a_s1, const float* __restrict__ a_d1,
    const int* __restrict__ offs, const int* __restrict__ csr,
    const float* __restrict__ b1, float* __restrict__ h1a, int N){
  int n = blockIdx.x*4 + (threadIdx.x >> 6);
  if (n >= N) return;
  const int lane = threadIdx.x & 63;
  const int sub  = lane >> 4;       // edge subgroup 0..3
  const int cl   = lane & 15;       // channel-lane
  const int head = cl >> 2;
  const float ad = a_d1[n*4+head];
  const int cw = 4*cl;
  float a0=0,a1=0,a2=0,a3=0,a4=0,a5=0,a6=0,a7=0,den=0;
  if (sub == 0){ // self loop
    float p = __expf(leaky(a_s1[n*4+head] + ad));
    uint4 u = *(const uint4*)(h1b + (size_t)n*64 + cw);
    a0 = p*bflo(u.x); a1 = p*bfhi(u.x); a2 = p*bflo(u.y); a3 = p*bfhi(u.y);
    a4 = p*bflo(u.z); a5 = p*bfhi(u.z); a6 = p*bflo(u.w); a7 = p*bfhi(u.w);
    den = p;
  }
  const int beg = offs[n], end = offs[n+1];
  int e = beg + sub;
  for (; e + 12 < end; e += 16){
    int s0 = csr[e], s1 = csr[e+4], s2 = csr[e+8], s3 = csr[e+12];
    float p0 = __expf(leaky(a_s1[s0*4+head] + ad));
    float p1 = __expf(leaky(a_s1[s1*4+head] + ad));
    float p2 = __expf(leaky(a_s1[s2*4+head] + ad));
    float p3 = __expf(leaky(a_s1[s3*4+head] + ad));
    uint4 u0 = *(const uint4*)(h1b + (size_t)s0*64 + cw);
    uint4 u1 = *(const uint4*)(h1b + (size_t)s1*64 + cw);
    uint4 u2 = *(const uint4*)(h1b + (size_t)s2*64 + cw);
    uint4 u3 = *(const uint4*)(h1b + (size_t)s3*64 + cw);
    a0 += p0*bflo(u0.x) + p1*bflo(u1.x) + p2*bflo(u2.x) + p3*bflo(u3.x);
    a1 += p0*bfhi(u0.x) + p1*bfhi(u1.x) + p2*bfhi(u2.x) + p3*bfhi(u3.x);
    a2 += p0*bflo(u0.y) + p1*bflo(u1.y) + p2*bflo(u2.y) + p3*bflo(u3.y);
    a3 += p0*bfhi(u0.y) + p1*bfhi(u1.y) + p2*bfhi(u2.y) + p3*bfhi(u3.y);
    a4 += p0*bflo(u0.z) + p1*bflo(u1.z) + p2*bflo(u2.z) + p3*bflo(u3.z);
    a5 += p0*bfhi(u0.z) + p1*bfhi(u1.z) + p2*bfhi(u2.z) + p3*bfhi(u3.z);
    a6 += p0*bflo(u0.w) + p1*bflo(u1.w) + p2*bflo(u2.w) + p3*bflo(u3.w);
    a7 += p0*bfhi(u0.w) + p1*bfhi(u1.w) + p2*bfhi(u2.w) + p3*bfhi(u3.w);
    den += p0 + p1 + p2 + p3;
  }
  for (; e < end; e += 4){
    int s = csr[e];
    float p = __expf(leaky(a_s1[s*4+head] + ad));
    uint4 u = *(const uint4*)(h1b + (size_t)s*64 + cw);
    a0 += p*bflo(u.x); a1 += p*bfhi(u.x); a2 += p*bflo(u.y); a3 += p*bfhi(u.y);
    a4 += p*bflo(u.z); a5 += p*bfhi(u.z); a6 += p*bflo(u.w); a7 += p*bfhi(u.w);
    den += p;
  }
  #pragma unroll
  for (int off = 16; off < 64; off <<= 1){
    a0 += __shfl_xor(a0,off); a1 += __shfl_xor(a1,off);
    a2 += __shfl_xor(a2,off); a3 += __shfl_xor(a3,off);
    a4 += __shfl_xor(a4,off); a5 += __shfl_xor(a5,off);
    a6 += __shfl_xor(a6,off); a7 += __shfl_xor(a7,off);
    den += __shfl_xor(den,off);
  }
  if (sub == 0){
    float inv = 1.f/den;
    int ch = 8*cl;
    float4 b0 = *(const float4*)(b1 + ch);
    float4 b4 = *(const float4*)(b1 + ch + 4);
    float4 o0 = make_float4(elu(a0*inv+b0.x), elu(a1*inv+b0.y), elu(a2*inv+b0.z), elu(a3*inv+b0.w));
    float4 o4 = make_float4(elu(a4*inv+b4.x), elu(a5*inv+b4.y), elu(a6*inv+b4.z), elu(a7*inv+b4.w));
    *(float4*)(h1a + (size_t)n*F1 + ch)     = o0;
    *(float4*)(h1a + (size_t)n*F1 + ch + 4) = o4;
  }
}

// ---------------- GEMM2: h2(bf16) = h1a @ W2, fused att coefficients ----------------
__global__ __launch_bounds__(256) void gemm2_kernel(const float* __restrict__ h1a, const float* __restrict__ W2,
    const float* __restrict__ att_src, const float* __restrict__ att_dst,
    unsigned int* __restrict__ h2b, float* __restrict__ as2, float* __restrict__ ad2, int M){
  __shared__ float As[64*132];
  __shared__ float Ws[128*32];
  const int tid = threadIdx.x;
  const int cg = tid & 15;
  const int rg = tid >> 4;
  const int m0 = blockIdx.x*64;
  #pragma unroll
  for (int p = 0; p < 8; ++p){
    int i = tid + 256*p;
    int r = i >> 5, q = i & 31;
    int row = m0 + r;
    float4 v = make_float4(0.f,0.f,0.f,0.f);
    if (row < M) v = *(const float4*)(h1a + (size_t)row*F1 + 4*q);
    *(float4*)&As[r*132 + 4*q] = v;
  }
  #pragma unroll
  for (int p = 0; p < 4; ++p){
    int i = tid + 256*p;
    ((float4*)Ws)[i] = ((const float4*)W2)[i];
  }
  __syncthreads();
  float acc[4][2] = {};
  const float* a0p = &As[(4*rg+0)*132];
  const float* a1p = &As[(4*rg+1)*132];
  const float* a2p = &As[(4*rg+2)*132];
  const float* a3p = &As[(4*rg+3)*132];
  #pragma unroll 8
  for (int kk = 0; kk < 128; ++kk){
    float2 w = *(const float2*)&Ws[kk*32 + 2*cg];
    float a0 = a0p[kk], a1 = a1p[kk], a2 = a2p[kk], a3 = a3p[kk];
    acc[0][0]+=a0*w.x; acc[0][1]+=a0*w.y;
    acc[1][0]+=a1*w.x; acc[1][1]+=a1*w.y;
    acc[2][0]+=a2*w.x; acc[2][1]+=a2*w.y;
    acc[3][0]+=a3*w.x; acc[3][1]+=a3*w.y;
  }
  const float2 sv = *(const float2*)(att_src + 2*cg);
  const float2 dv = *(const float2*)(att_dst + 2*cg);
  #pragma unroll
  for (int i = 0; i < 4; ++i){
    int row = m0 + 4*rg + i;
    if (row < M){
      float2 o = make_float2(acc[i][0], acc[i][1]);
      h2b[(size_t)row*16 + cg] = pack2(f2bf(o.x), f2bf(o.y));
      float ps = o.x*sv.x + o.y*sv.y;
      float pd = o.x*dv.x + o.y*dv.y;
      ps += __shfl_xor(ps,1); ps += __shfl_xor(ps,2); ps += __shfl_xor(ps,4); ps += __shfl_xor(ps,8);
      pd += __shfl_xor(pd,1); pd += __shfl_xor(pd,2); pd += __shfl_xor(pd,4); pd += __shfl_xor(pd,8);
      if (cg == 0){ as2[row] = ps; ad2[row] = pd; }
    }
  }
}

// ---------------- Aggregation 2 + bias + elu + final linear (bf16 h2 gather) ----------------
__global__ __launch_bounds__(256) void agg2_kernel(const unsigned int* __restrict__ h2b,
    const float* __restrict__ as2, const float* __restrict__ ad2,
    const int* __restrict__ offs, const int* __restrict__ csr,
    const float* __restrict__ b2, const float* __restrict__ linw, const float* __restrict__ linb,
    float* __restrict__ out, int N){
  int n = blockIdx.x*4 + (threadIdx.x >> 6);
  if (n >= N) return;
  const int lane = threadIdx.x & 63;
  const int sub  = lane >> 3;
  const int cl   = lane & 7;
  const int cw   = 2*cl;
  const float ad = ad2[n];
  float a0=0,a1=0,a2=0,a3=0,den=0;
  if (sub == 0){
    float p = __expf(leaky(as2[n] + ad));
    uint2 u = *(const uint2*)(h2b + (size_t)n*16 + cw);
    a0 = p*bflo(u.x); a1 = p*bfhi(u.x); a2 = p*bflo(u.y); a3 = p*bfhi(u.y);
    den = p;
  }
  const int beg = offs[n], end = offs[n+1];
  int e = beg + sub;
  for (; e + 8 < end; e += 16){
    int s0 = csr[e], s1 = csr[e+8];
    float p0 = __expf(leaky(as2[s0] + ad));
    float p1 = __expf(leaky(as2[s1] + ad));
    uint2 u0 = *(const uint2*)(h2b + (size_t)s0*16 + cw);
    uint2 u1 = *(const uint2*)(h2b + (size_t)s1*16 + cw);
    a0 += p0*bflo(u0.x) + p1*bflo(u1.x);
    a1 += p0*bfhi(u0.x) + p1*bfhi(u1.x);
    a2 += p0*bflo(u0.y) + p1*bflo(u1.y);
    a3 += p0*bfhi(u0.y) + p1*bfhi(u1.y);
    den += p0 + p1;
  }
  for (; e < end; e += 8){
    int s = csr[e];
    float p = __expf(leaky(as2[s] + ad));
    uint2 u = *(const uint2*)(h2b + (size_t)s*16 + cw);
    a0 += p*bflo(u.x); a1 += p*bfhi(u.x); a2 += p*bflo(u.y); a3 += p*bfhi(u.y);
    den += p;
  }
  #pragma unroll
  for (int off = 8; off < 64; off <<= 1){
    a0 += __shfl_xor(a0,off); a1 += __shfl_xor(a1,off);
    a2 += __shfl_xor(a2,off); a3 += __shfl_xor(a3,off);
    den += __shfl_xor(den,off);
  }
  float inv = 1.f/den;
  int ch = 4*cl;
  float o0 = elu(a0*inv + b2[ch+0]);
  float o1 = elu(a1*inv + b2[ch+1]);
  float o2 = elu(a2*inv + b2[ch+2]);
  float o3 = elu(a3*inv + b2[ch+3]);
  float r0 = o0*linw[2*(ch+0)]   + o1*linw[2*(ch+1)]   + o2*linw[2*(ch+2)]   + o3*linw[2*(ch+3)];
  float r1 = o0*linw[2*(ch+0)+1] + o1*linw[2*(ch+1)+1] + o2*linw[2*(ch+2)+1] + o3*linw[2*(ch+3)+1];
  r0 += __shfl_xor(r0,1); r0 += __shfl_xor(r0,2); r0 += __shfl_xor(r0,4);
  r1 += __shfl_xor(r1,1); r1 += __shfl_xor(r1,2); r1 += __shfl_xor(r1,4);
  if (lane == 0){
    out[(size_t)n*2+0] = r0 + linb[0];
    out[(size_t)n*2+1] = r1 + linb[1];
  }
}

// ---------------- launch ----------------
extern "C" void kernel_launch(void* const* d_in, const int* in_sizes, int n_in,
                              void* d_out, int out_size, void* d_ws, size_t ws_size,
                              hipStream_t stream) {
  const float* x    = (const float*)d_in[0];
  const int*   ei   = (const int*)  d_in[1];
  const float* W1   = (const float*)d_in[2];
  const float* as1w = (const float*)d_in[3];
  const float* ad1w = (const float*)d_in[4];
  const float* b1   = (const float*)d_in[5];
  const float* W2   = (const float*)d_in[6];
  const float* as2w = (const float*)d_in[7];
  const float* ad2w = (const float*)d_in[8];
  const float* b2   = (const float*)d_in[9];
  const float* linw = (const float*)d_in[10];
  const float* linb = (const float*)d_in[11];
  float* out = (float*)d_out;

  const int N = in_sizes[0] / IN_DIM;   // 50000
  const int E = in_sizes[1] / 2;        // 800000

  const int NBUK = (N + 511) >> BSHIFT;           // 98
  const int NCHK = (E + 2047) / 2048;             // 391
  const int CSTR = (NCHK + 3) & ~3;               // padded stride

  char* ws = (char*)d_ws;
  auto alloc = [&](size_t bytes) -> char* {
    char* p = ws; ws += (bytes + 255) & ~(size_t)255; return p;
  };
  unsigned short* h1b = (unsigned short*)alloc((size_t)N*F1*2);  // bf16; also hosts im during sort
  float* h1a  = (float*)alloc((size_t)N*F1*4);
  unsigned int* h2b = (unsigned int*)alloc((size_t)N*HID*2);     // bf16 packed
  float* a_s1 = (float*)alloc((size_t)N*4*4);
  float* a_d1 = (float*)alloc((size_t)N*4*4);
  float* a_s2 = (float*)alloc((size_t)N*4);
  float* a_d2 = (float*)alloc((size_t)N*4);
  size_t cntblk_bytes = (size_t)NBUK*CSTR*4;
  if (cntblk_bytes < 131072) cntblk_bytes = 131072;
  int* cnt_blk = (int*)alloc(cntblk_bytes);        // also hosts W1h/W1l after passB
  int* btot    = (int*)alloc((size_t)(NBUK+1)*4);
  int* bbase   = (int*)alloc((size_t)(NBUK+1)*4);
  int* offs    = (int*)alloc((size_t)(N+1)*4);
  int* csr     = (int*)alloc((size_t)E*4);
  // aliases (lifetimes disjoint by kernel ordering on the stream):
  uint2* im = (uint2*)h1b;                         // sort intermediate, dead before gemm1 writes h1b
  unsigned short* W1h = (unsigned short*)cnt_blk;  // cnt_blk dead after bukscat
  unsigned short* W1l = W1h + (size_t)IN_DIM*F1;

  const int* srcs = ei;       // edge_index[0]
  const int* dsts = ei + E;   // edge_index[1]

  bukcnt_kernel<<<NCHK, 256, 0, stream>>>(dsts, cnt_blk, E, NBUK, CSTR);
  bukscan1_kernel<<<NBUK, 256, 0, stream>>>(cnt_blk, btot, NCHK, CSTR);
  bukscan2_kernel<<<1, 256, 0, stream>>>(btot, bbase, offs, NBUK, N, E);
  bukscat_kernel<<<NCHK, 256, 0, stream>>>(srcs, dsts, cnt_blk, bbase, im, E, NBUK, CSTR);
  bukfine_kernel<<<NBUK, 256, 0, stream>>>(im, bbase, offs, csr, N);
  convw_kernel<<<(IN_DIM*F1)/256, 256, 0, stream>>>(W1, W1h, W1l);
  gemm1_kernel<<<(N+63)/64, 256, 0, stream>>>(x, W1h, W1l, as1w, ad1w, h1b, a_s1, a_d1, N);
  agg1_kernel<<<(N+3)/4, 256, 0, stream>>>((const unsigned int*)h1b, a_s1, a_d1, offs, csr, b1, h1a, N);
  gemm2_kernel<<<(N+63)/64, 256, 0, stream>>>(h1a, W2, as2w, ad2w, h2b, a_s2, a_d2, N);
  agg2_kernel<<<(N+3)/4, 256, 0, stream>>>(h2b, a_s2, a_d2, offs, csr, b2, linw, linb, out, N);
}